// Round 5
// baseline (4640.948 us; speedup 1.0000x reference)
//
#include <hip/hip_runtime.h>
#include <cstdio>

#ifndef __has_builtin
#define __has_builtin(x) 0
#endif

// ---------------- problem constants ----------------
#define NB      256
#define NT      48
#define NS      512
#define KAHEAD  4
#define NTHREADS 1024
#define NBLOCKS  256
#define GSIZE    32
#define RSTRIDE  528     // exchange row: 4 kq-blocks x 132 (128 data + 4 pad)
#define XSLOT    524     // x[512] scalar at panel col 524
#define NKS      33      // 528/16 K-steps
#define XROWB    1120    // LDS bf16 panel row stride bytes (16B-multiple, 2-way-bank-safe)

// ---------------- workspace (float offsets) ----------------
#define WS_D     0              // [256][528] d exchange (fp32)
#define WS_X     135168         // [256][528] x exchange
#define WS_LH    270336         // [256][512] lh exchange
#define WS_BAR   401408         // 256 uints: [g*32]=barrier, [g*32+1]=rank ctr
#define WS_WAH   401664         // gemmA B hi: [32 cix][2 half][33 ks][64 l][8] us
#define WS_WAL   942336
#define WS_WCH   1483008        // gemmC B hi (same shape)
#define WS_WCL   2023680
#define WS_WSH   2564352        // ls B hi: [32 nt][32 ks][64 l][4] us
#define WS_WSL   2695424
#define WS_FLOATS 2826496       // 11.3 MB

// ---------------- LDS (byte offsets), total 149264 ----------------
#define L_XHI    0              // bf16 panel hi [32][XROWB] 35840
#define L_XLO    35840
#define L_LSB    71680          // ushort [48][512] bf16 ls  49152
#define L_GH     120832         // float [3][32][17]
#define L_GI     127360
#define L_LH     133888         // float [512]
#define L_WO     135936
#define L_E      137984
#define L_ATT    138240
#define L_CP     138496
#define L_H1P    140544
#define L_H1S    144640
#define L_H2P    145664
#define L_H2S    147712
#define L_H3P    148224
#define L_MISC   149248         // int gx, cix
#define LDS_BYTES 149264

typedef float  f4v  __attribute__((ext_vector_type(4)));
typedef float  f16v __attribute__((ext_vector_type(16)));
typedef short  s4v  __attribute__((ext_vector_type(4)));
typedef short  s8v  __attribute__((ext_vector_type(8)));
typedef unsigned short u4v __attribute__((ext_vector_type(4)));

// ---------------- MFMA ----------------
__device__ __forceinline__ f16v MFMA32(s8v a, s8v b, f16v c) {
    return __builtin_amdgcn_mfma_f32_32x32x16_bf16(a, b, c, 0, 0, 0);
}
#if __has_builtin(__builtin_amdgcn_mfma_f32_16x16x16bf16_1k)
__device__ __forceinline__ f4v MFMA16(s4v a, s4v b, f4v c) {
    return __builtin_amdgcn_mfma_f32_16x16x16bf16_1k(a, b, c, 0, 0, 0);
}
#else
__device__ __forceinline__ f4v MFMA16(s4v a, s4v b, f4v c) {
    s8v A = { a[0], a[1], a[2], a[3], 0, 0, 0, 0 };
    s8v B = { b[0], b[1], b[2], b[3], 0, 0, 0, 0 };
    return __builtin_amdgcn_mfma_f32_16x16x32_bf16(A, B, c, 0, 0, 0);
}
#endif

// ---------------- math ----------------
__device__ __forceinline__ float frcp_(float x) {
#if __has_builtin(__builtin_amdgcn_rcpf)
    return __builtin_amdgcn_rcpf(x);
#else
    return 1.0f / x;
#endif
}
__device__ __forceinline__ float ftanh_(float x) {
    float e = __expf(2.0f * x);
    return 1.0f - 2.0f * frcp_(e + 1.0f);
}
__device__ __forceinline__ float fsig_(float x) { return frcp_(1.0f + __expf(-x)); }
__device__ __forceinline__ float lrelu_(float x) { return fmaxf(x, 0.01f * x); }
__device__ __forceinline__ unsigned short rne16_(unsigned u) {
    return (unsigned short)((u + 0x7FFFu + ((u >> 16) & 1u)) >> 16);
}
__device__ __forceinline__ float bf2f_(unsigned short b) {
    return __uint_as_float(((unsigned)b) << 16);
}
__host__ __device__ __forceinline__ void split2_(float v, unsigned short& hi, unsigned short& lo) {
    unsigned u = __float_as_uint(v);
    unsigned short h = (unsigned short)((u + 0x7FFFu + ((u >> 16) & 1u)) >> 16);
    float hf = __uint_as_float(((unsigned)h) << 16);
    unsigned ul = __float_as_uint(v - hf);
    hi = h;
    lo = (unsigned short)((ul + 0x7FFFu + ((ul >> 16) & 1u)) >> 16);
}

// ---------------- XCD-local (L2-scope) coherent access: sc0 = L1-bypass ----------------
__device__ __forceinline__ void cstore1(float* p, float v) {
    asm volatile("global_store_dword %0, %1, off sc0" :: "v"(p), "v"(v) : "memory");
}
__device__ __forceinline__ f4v cload4(const float* p) {
    f4v v;
    asm volatile("global_load_dwordx4 %0, %1, off sc0" : "=v"(v) : "v"(p));
    return v;
}
__device__ __forceinline__ float cload1(const float* p) {
    float v;
    asm volatile("global_load_dword %0, %1, off sc0" : "=v"(v) : "v"(p));
    return v;
}
__device__ __forceinline__ void cwait() {
    asm volatile("s_waitcnt vmcnt(0)" ::: "memory");
    __builtin_amdgcn_sched_barrier(0);
}

// Group barrier (agent-scope counter; proven r2-r4). Each wave drains its own
// stores (vmcnt 0) before s_barrier, so all L2 writes land before tid0 signals.
__device__ __forceinline__ void gbar(unsigned* bar, unsigned* epoch) {
    asm volatile("s_waitcnt vmcnt(0)" ::: "memory");
    __syncthreads();
    if (threadIdx.x == 0) {
        *epoch += GSIZE;
        __hip_atomic_fetch_add(bar, 1u, __ATOMIC_RELAXED, __HIP_MEMORY_SCOPE_AGENT);
        unsigned target = *epoch;
        int guard = 0;
        while (__hip_atomic_load(bar, __ATOMIC_RELAXED, __HIP_MEMORY_SCOPE_AGENT) < target) {
#if __has_builtin(__builtin_amdgcn_s_sleep)
            __builtin_amdgcn_s_sleep(2);
#endif
            if (++guard > (1 << 22)) break;
        }
    }
    __syncthreads();
}

// ---------------- staging: fp32 exchange panel -> LDS bf16 hi/lo ----------------
__device__ __forceinline__ void cvtStore_(char* hiB, char* loB, int idx, f4v v) {
    unsigned row = (unsigned)idx / 528u;
    unsigned col = (unsigned)idx - row * 528u;
    u4v h, l;
    #pragma unroll
    for (int i = 0; i < 4; ++i) { unsigned short hh, ll; split2_(v[i], hh, ll); h[i] = hh; l[i] = ll; }
    *(u4v*)(hiB + row * XROWB + col * 2) = h;
    *(u4v*)(loB + row * XROWB + col * 2) = l;
}
__device__ __forceinline__ void stagePanel(const float* __restrict__ gsrc,
                                           char* __restrict__ hiB,
                                           char* __restrict__ loB, int tid) {
    f4v v0 = cload4(gsrc + tid * 4);
    f4v v1 = cload4(gsrc + 4096 + tid * 4);
    f4v v2 = cload4(gsrc + 8192 + tid * 4);
    f4v v3 = cload4(gsrc + 12288 + tid * 4);
    f4v v4 = {0.f, 0.f, 0.f, 0.f};
    if (tid < 128) v4 = cload4(gsrc + 16384 + tid * 4);
    cwait();
    cvtStore_(hiB, loB, tid * 4, v0);
    cvtStore_(hiB, loB, 4096 + tid * 4, v1);
    cvtStore_(hiB, loB, 8192 + tid * 4, v2);
    cvtStore_(hiB, loB, 12288 + tid * 4, v3);
    if (tid < 128) cvtStore_(hiB, loB, 16384 + tid * 4, v4);
}

// ---------------- 32x32x16 GEMMs (2 waves each; 3-term hi/lo split) ----------------
__device__ __forceinline__ void gemmA32(const char* smem, const unsigned short* BH,
        const unsigned short* BL, int cix, int g, int tid, float* ghs, float* lhw,
        const float* bh, const float* bhh, bool doLH) {
    const int w = tid >> 6;
    if (w >= 2) return;
    const int l = tid & 63;
    const char* A  = smem + L_XHI + (l & 31) * XROWB + ((l >> 5) << 4);
    const char* Al = smem + L_XLO + (l & 31) * XROWB + ((l >> 5) << 4);
    const unsigned short* ph = BH + ((long)(cix * 2 + w) * NKS) * 512 + (l << 3);
    const unsigned short* pl = BL + ((long)(cix * 2 + w) * NKS) * 512 + (l << 3);
    f16v acc = {0,0,0,0,0,0,0,0,0,0,0,0,0,0,0,0};
    #pragma unroll 4
    for (int ks = 0; ks < NKS; ++ks) {
        s8v ah = *(const s8v*)(A + ks * 32);
        s8v al = *(const s8v*)(Al + ks * 32);
        s8v bh8 = *(const s8v*)(ph + ks * 512);
        s8v bl8 = *(const s8v*)(pl + ks * 512);
        acc = MFMA32(ah, bh8, acc);
        acc = MFMA32(al, bh8, acc);
        acc = MFMA32(ah, bl8, acc);
    }
    const int c = w * 32 + (l & 31);
    const int rb = (l >> 5) << 2;
    if (c < 16) {
        if (doLH) {
            const int j = cix * 16 + c;
            const float b = bh[j];
            #pragma unroll
            for (int r = 0; r < 16; ++r) {
                int row = (r & 3) + ((r >> 2) << 3) + rb;   // verified 32x32 C/D map
                cstore1(lhw + (long)(g * 32 + row) * NS + j, acc[r] + b);
            }
        }
    } else {
        const int gate = (c - 16) >> 4, jj = (c - 16) & 15;
        const float b = bhh[gate * 512 + cix * 16 + jj];
        #pragma unroll
        for (int r = 0; r < 16; ++r) {
            int row = (r & 3) + ((r >> 2) << 3) + rb;
            ghs[gate * 544 + row * 17 + jj] = acc[r] + b;
        }
    }
}

__device__ __forceinline__ void gemmC32(const char* smem, const unsigned short* BH,
        const unsigned short* BL, int cix, int tid, float* gis, const float* bih) {
    const int w = tid >> 6;
    if (w >= 2) return;
    const int l = tid & 63;
    const char* A  = smem + L_XHI + (l & 31) * XROWB + ((l >> 5) << 4);
    const char* Al = smem + L_XLO + (l & 31) * XROWB + ((l >> 5) << 4);
    const unsigned short* ph = BH + ((long)(cix * 2 + w) * NKS) * 512 + (l << 3);
    const unsigned short* pl = BL + ((long)(cix * 2 + w) * NKS) * 512 + (l << 3);
    f16v acc = {0,0,0,0,0,0,0,0,0,0,0,0,0,0,0,0};
    #pragma unroll 4
    for (int ks = 0; ks < NKS; ++ks) {
        s8v ah = *(const s8v*)(A + ks * 32);
        s8v al = *(const s8v*)(Al + ks * 32);
        s8v bh8 = *(const s8v*)(ph + ks * 512);
        s8v bl8 = *(const s8v*)(pl + ks * 512);
        acc = MFMA32(ah, bh8, acc);
        acc = MFMA32(al, bh8, acc);
        acc = MFMA32(ah, bl8, acc);
    }
    const int c = w * 32 + (l & 63 & 31);
    const int rb = (l >> 5) << 2;
    if (c < 48) {
        const int gate = c >> 4, jj = c & 15;
        const float b = bih[gate * 512 + cix * 16 + jj];
        #pragma unroll
        for (int r = 0; r < 16; ++r) {
            int row = (r & 3) + ((r >> 2) << 3) + rb;
            gis[gate * 544 + row * 17 + jj] = acc[r] + b;
        }
    }
}

// ---------------- startup ls GEMM (16x16, per 24-row chunk) ----------------
__device__ __forceinline__ void lsGemm(const char* smem, const unsigned short* WH,
        const unsigned short* WL, int tid, int ch, unsigned short* lsb, const float* bs) {
    const int w = tid >> 6, l = tid & 63;
    const int mt = w & 1, ng = w >> 1;
    const char* A  = smem + L_XHI + (mt * 16 + (l & 15)) * XROWB + ((l >> 4) << 3);
    const char* Al = smem + L_XLO + (mt * 16 + (l & 15)) * XROWB + ((l >> 4) << 3);
    f4v acc[4] = {{0,0,0,0},{0,0,0,0},{0,0,0,0},{0,0,0,0}};
    for (int ks = 0; ks < 32; ++ks) {
        s4v ah = *(const s4v*)(A + ks * 32);
        s4v al = *(const s4v*)(Al + ks * 32);
        #pragma unroll
        for (int i = 0; i < 4; ++i) {
            const unsigned short* bp  = WH + (((ng * 4 + i) * 32 + ks) << 8) + (l << 2);
            const unsigned short* blp = WL + (((ng * 4 + i) * 32 + ks) << 8) + (l << 2);
            s4v bh = *(const s4v*)bp;
            s4v bl = *(const s4v*)blp;
            acc[i] = MFMA16(ah, bh, acc[i]);
            acc[i] = MFMA16(al, bh, acc[i]);
            acc[i] = MFMA16(ah, bl, acc[i]);
        }
    }
    const int rb = mt * 16 + ((l >> 4) << 2);
    #pragma unroll
    for (int i = 0; i < 4; ++i) {
        const int n = (ng * 4 + i) * 16 + (l & 15);
        const float bsv = bs[n];
        #pragma unroll
        for (int r = 0; r < 4; ++r) {
            int row = rb + r;
            if (row < 24)
                lsb[(ch * 24 + row) * NS + n] = rne16_(__float_as_uint(acc[i][r] + bsv));
        }
    }
}

// ---------------- prep: fragment packing + zeroing ----------------
__global__ void prep_kernel(const float* __restrict__ Whh,
                            const float* __restrict__ Wih,
                            const float* __restrict__ Wh,
                            const float* __restrict__ Ws,
                            float* __restrict__ ws) {
    long i = (long)blockIdx.x * blockDim.x + threadIdx.x;
    long stride = (long)gridDim.x * blockDim.x;
    unsigned short* waH = (unsigned short*)(ws + WS_WAH);
    unsigned short* waL = (unsigned short*)(ws + WS_WAL);
    unsigned short* wcH = (unsigned short*)(ws + WS_WCH);
    unsigned short* wcL = (unsigned short*)(ws + WS_WCL);
    unsigned short* wsH = (unsigned short*)(ws + WS_WSH);
    unsigned short* wsL = (unsigned short*)(ws + WS_WSL);

    // gemmA B: p = ((cix*2+half)*33 + ks)*64 + l, elems e=0..7
    for (long p = i; p < 135168; p += stride) {
        int l = (int)(p & 63);
        long t = p >> 6;
        int ks = (int)(t % 33);
        int u  = (int)(t / 33);
        int half = u & 1, cix = u >> 1;
        int c = half * 32 + (l & 31);
        #pragma unroll
        for (int e = 0; e < 8; ++e) {
            int pc = ks * 16 + ((l >> 5) << 3) + e;
            int kq = pc / 132, ko = pc - kq * 132;
            float wv = 0.f;
            if (ko < 128) {
                int k = kq * 128 + ko;
                if (c < 16) wv = Wh[(long)k * 512 + cix * 16 + c];
                else {
                    int gate = (c - 16) >> 4, j = cix * 16 + ((c - 16) & 15);
                    wv = Whh[((long)(gate * 512 + j)) * 512 + k];
                }
            }
            unsigned short hh, ll; split2_(wv, hh, ll);
            waH[p * 8 + e] = hh; waL[p * 8 + e] = ll;
        }
    }
    // gemmC B: cols c<48 = (gate, j); K includes x[512] at pc==XSLOT
    for (long p = i; p < 135168; p += stride) {
        int l = (int)(p & 63);
        long t = p >> 6;
        int ks = (int)(t % 33);
        int u  = (int)(t / 33);
        int half = u & 1, cix = u >> 1;
        int c = half * 32 + (l & 31);
        #pragma unroll
        for (int e = 0; e < 8; ++e) {
            int pc = ks * 16 + ((l >> 5) << 3) + e;
            int kq = pc / 132, ko = pc - kq * 132;
            float wv = 0.f;
            if (c < 48) {
                int k = -1;
                if (ko < 128) k = kq * 128 + ko;
                else if (pc == XSLOT) k = 512;
                if (k >= 0) {
                    int gate = c >> 4, j = cix * 16 + (c & 15);
                    wv = Wih[((long)(gate * 512 + j)) * 513 + k];
                }
            }
            unsigned short hh, ll; split2_(wv, hh, ll);
            wcH[p * 8 + e] = hh; wcL[p * 8 + e] = ll;
        }
    }
    // ls B: p = (nt*32+ks)*64 + l, elems e=0..3
    for (long p = i; p < 65536; p += stride) {
        int l = (int)(p & 63);
        long t = p >> 6;
        int ks = (int)(t & 31), nt = (int)(t >> 5);
        int n = nt * 16 + (l & 15);
        #pragma unroll
        for (int e = 0; e < 4; ++e) {
            int k = ks * 16 + ((l >> 4) << 2) + e;
            float wv = Ws[(long)k * 512 + n];
            unsigned short hh, ll; split2_(wv, hh, ll);
            wsH[p * 4 + e] = hh; wsL[p * 4 + e] = ll;
        }
    }
    for (long p = i; p < 270336; p += stride) ws[WS_D + p] = 0.0f;   // d+x panels (pads stay 0)
    if (i < 256) ((unsigned*)(ws + WS_BAR))[i] = 0u;
}

// ---------------- main persistent cooperative kernel ----------------
__global__ void __launch_bounds__(NTHREADS, 4) fused_kernel(
        const float* __restrict__ hiddens, const float* __restrict__ allys,
        const float* __restrict__ bs,
        const float* __restrict__ Wo, const float* __restrict__ bo,
        const float* __restrict__ bh,
        const float* __restrict__ b_ih, const float* __restrict__ b_hh,
        const float* __restrict__ W1, const float* __restrict__ b1,
        const float* __restrict__ W2, const float* __restrict__ b2,
        const float* __restrict__ W3, const float* __restrict__ b3,
        const float* __restrict__ W4, const float* __restrict__ b4,
        float* __restrict__ ws, float* __restrict__ out) {
    const int tid = threadIdx.x;

    float* dw  = ws + WS_D;
    float* xw  = ws + WS_X;
    float* lhw = ws + WS_LH;
    const unsigned short* waH = (const unsigned short*)(ws + WS_WAH);
    const unsigned short* waL = (const unsigned short*)(ws + WS_WAL);
    const unsigned short* wcH = (const unsigned short*)(ws + WS_WCH);
    const unsigned short* wcL = (const unsigned short*)(ws + WS_WCL);
    const unsigned short* wsH = (const unsigned short*)(ws + WS_WSH);
    const unsigned short* wsL = (const unsigned short*)(ws + WS_WSL);
    unsigned* barbase = (unsigned*)(ws + WS_BAR);

    extern __shared__ char smem[];
    char*           xhi   = smem + L_XHI;
    char*           xlo   = smem + L_XLO;
    unsigned short* lsb   = (unsigned short*)(smem + L_LSB);
    float*          ghs   = (float*)(smem + L_GH);
    float*          gis   = (float*)(smem + L_GI);
    float*          lh_s  = (float*)(smem + L_LH);
    float*          wo_s  = (float*)(smem + L_WO);
    float*          e_s   = (float*)(smem + L_E);
    float*          att_s = (float*)(smem + L_ATT);
    float*          cp_s  = (float*)(smem + L_CP);
    float*          h1p   = (float*)(smem + L_H1P);
    float*          h1s   = (float*)(smem + L_H1S);
    float*          h2p   = (float*)(smem + L_H2P);
    float*          h2s   = (float*)(smem + L_H2S);
    float*          h3p   = (float*)(smem + L_H3P);
    int*            misc  = (int*)(smem + L_MISC);

    // ---- dynamic XCD-local grouping (capacity guarantees 32 blocks/XCD) ----
    if (tid == 0) {
        unsigned xcc;
        asm volatile("s_getreg_b32 %0, hwreg(HW_REG_XCC_ID)" : "=s"(xcc));
        int gx = (int)(xcc & 7u);
        unsigned rk = __hip_atomic_fetch_add(barbase + gx * 32 + 1, 1u,
                                             __ATOMIC_RELAXED, __HIP_MEMORY_SCOPE_AGENT);
        misc[0] = gx;
        misc[1] = (int)(rk & 31u);
    }
    __syncthreads();
    const int g = misc[0], cix = misc[1];
    const int myb = g * 32 + cix;
    unsigned* bar = barbase + (g << 5);
    unsigned epoch = 0;

    const int sS = tid & 511, th = tid >> 9;
    const int rowE = tid >> 4, jE = tid & 15;          // gate-epilogue map (tid<512)
    const int jgE = cix * 16 + jE;
    const int jmapE = ((jgE >> 7) * 132) + (jgE & 127);
    const float* gPanelD = dw + (long)g * GSIZE * RSTRIDE;
    const float* gPanelX = xw + (long)g * GSIZE * RSTRIDE;

    float hreg[24];
    if (tid < NS) wo_s[tid] = Wo[tid];
    #pragma unroll
    for (int q = 0; q < 24; ++q)
        hreg[q] = hiddens[((long)myb * NT + th * 24 + q) * NS + sS];

    // ==== startup: ls = hiddens[myb] @ Ws + bs via MFMA (2 chunks of 24 rows) ====
    for (int ch = 0; ch < 2; ++ch) {
        __syncthreads();
        {   // stage 24 fp32 rows -> bf16 hi/lo panels (rows 0..23, cols 0..511)
            const float* src = hiddens + ((long)myb * NT + ch * 24) * NS;
            const int i0 = tid * 12;
            #pragma unroll
            for (int j3 = 0; j3 < 3; ++j3) {
                f4v v = *(const f4v*)(src + i0 + j3 * 4);
                int idx = i0 + j3 * 4;
                int row = idx >> 9, col = idx & 511;
                u4v h, l;
                #pragma unroll
                for (int e = 0; e < 4; ++e) { unsigned short hh, ll; split2_(v[e], hh, ll); h[e] = hh; l[e] = ll; }
                *(u4v*)(xhi + row * XROWB + col * 2) = h;
                *(u4v*)(xlo + row * XROWB + col * 2) = l;
            }
        }
        __syncthreads();
        lsGemm(smem, wsH, wsL, tid, ch, lsb, bs);
    }
    __syncthreads();

    const float bo0 = bo[0];

    // ================= time scan: 3 group barriers per step =================
    for (int t = 0; t < NT; ++t) {
        // ---- A: stage d -> panels; MFMA gh + lh ----
        stagePanel(gPanelD, xhi, xlo, tid);
        __syncthreads();
        gemmA32(smem, waH, waL, cix, g, tid, ghs, lhw, bh, b_hh, true);
        gbar(bar, &epoch);

        // ---- B: attention for own row ----
        if (tid < 128) {
            f4v v = cload4(lhw + (long)myb * NS + tid * 4);
            cwait();
            *(f4v*)(lh_s + tid * 4) = v;
        }
        if (tid == 0) cstore1(xw + (long)myb * RSTRIDE + XSLOT, allys[myb * NT + t]);
        __syncthreads();
        {
            const int wv = tid >> 6, ln = tid & 63;
            for (int q = 0; q < 3; ++q) {
                const int tt = wv * 3 + q;
                float p = 0.f;
                #pragma unroll
                for (int i2 = 0; i2 < 8; ++i2) {
                    int s = ln + (i2 << 6);
                    p = fmaf(wo_s[s], ftanh_(lh_s[s] + bf2f_(lsb[tt * NS + s])), p);
                }
                #pragma unroll
                for (int off = 32; off >= 1; off >>= 1) p += __shfl_xor(p, off, 64);
                if (ln == 0) e_s[tt] = p + bo0;
            }
        }
        __syncthreads();
        if (tid < 64) {
            float v = (tid < NT) ? e_s[tid] : -1e30f;
            float m = v;
            #pragma unroll
            for (int off = 32; off >= 1; off >>= 1) m = fmaxf(m, __shfl_xor(m, off, 64));
            float ex = (tid < NT) ? __expf(v - m) : 0.0f;
            float ssum = ex;
            #pragma unroll
            for (int off = 32; off >= 1; off >>= 1) ssum += __shfl_xor(ssum, off, 64);
            if (tid < NT) att_s[tid] = ex * frcp_(ssum);
        }
        __syncthreads();
        {
            float p = 0.f;
            #pragma unroll
            for (int q = 0; q < 24; ++q) p = fmaf(att_s[th * 24 + q], hreg[q], p);
            if (th == 0) cp_s[sS] = p;
            __syncthreads();
            if (th == 1)
                cstore1(xw + (long)myb * RSTRIDE + ((sS >> 7) * 132) + (sS & 127), p + cp_s[sS]);
        }
        gbar(bar, &epoch);

        // ---- C: stage x -> panels; MFMA gi; GRU gates ----
        float hp = 0.f;
        if (tid < 512) hp = cload1(dw + (long)(g * 32 + rowE) * RSTRIDE + jmapE);
        stagePanel(gPanelX, xhi, xlo, tid);
        __syncthreads();
        gemmC32(smem, wcH, wcL, cix, tid, gis, b_ih);
        __syncthreads();
        if (tid < 512) {
            float gr  = gis[rowE * 17 + jE]        + ghs[rowE * 17 + jE];
            float gz  = gis[544 + rowE * 17 + jE]  + ghs[544 + rowE * 17 + jE];
            float gni = gis[1088 + rowE * 17 + jE];
            float gnh = ghs[1088 + rowE * 17 + jE];
            float rg = fsig_(gr);
            float zg = fsig_(gz);
            float ng = ftanh_(gni + rg * gnh);
            cstore1(dw + (long)(g * 32 + rowE) * RSTRIDE + jmapE, (1.f - zg) * ng + zg * hp);
        }
        gbar(bar, &epoch);
    }

    // ================= k_wk_ahead head =================
    for (int kk = 0; kk < KAHEAD; ++kk) {
        {
            float v = 0.f;
            if (tid < NS) v = cload1(dw + (long)myb * RSTRIDE + ((tid >> 7) * 132) + (tid & 127));
            cwait();
            if (tid < NS) lh_s[tid] = v;
        }
        __syncthreads();
        {   // M1: 512 -> 256
            int n = tid & 255, q4 = tid >> 8;
            const float* av = lh_s + q4 * 128;
            const float* wp = W1 + (long)(q4 * 128) * 256 + n;
            float acc = 0.f;
            #pragma unroll 4
            for (int k2 = 0; k2 < 128; ++k2) { acc = fmaf(av[k2], wp[0], acc); wp += 256; }
            h1p[n * 4 + q4] = acc;
        }
        __syncthreads();
        if (tid < 256) {
            float v = h1p[tid * 4] + h1p[tid * 4 + 1] + h1p[tid * 4 + 2] + h1p[tid * 4 + 3];
            h1s[tid] = lrelu_(v + b1[tid]);
        }
        __syncthreads();
        if (tid < 512) {   // M2: 256 -> 128
            int n = tid & 127, q4 = tid >> 7;
            const float* av = h1s + q4 * 64;
            const float* wp = W2 + (long)(q4 * 64) * 128 + n;
            float acc = 0.f;
            #pragma unroll 4
            for (int k2 = 0; k2 < 64; ++k2) { acc = fmaf(av[k2], wp[0], acc); wp += 128; }
            h2p[n * 4 + q4] = acc;
        }
        __syncthreads();
        if (tid < 128) {
            float v = h2p[tid * 4] + h2p[tid * 4 + 1] + h2p[tid * 4 + 2] + h2p[tid * 4 + 3];
            h2s[tid] = lrelu_(v + b2[tid]);
        }
        __syncthreads();
        if (tid < 256) {   // M3: 128 -> 64
            int n = tid & 63, q4 = tid >> 6;
            const float* av = h2s + q4 * 32;
            const float* wp = W3 + (long)(q4 * 32) * 64 + n;
            float acc = 0.f;
            #pragma unroll 4
            for (int k2 = 0; k2 < 32; ++k2) { acc = fmaf(av[k2], wp[0], acc); wp += 64; }
            h3p[n * 4 + q4] = acc;
        }
        __syncthreads();
        if (tid < 64) {    // M3 epilogue + M4
            float v = h3p[tid * 4] + h3p[tid * 4 + 1] + h3p[tid * 4 + 2] + h3p[tid * 4 + 3];
            float h3v = lrelu_(v + b3[tid]);
            float p = h3v * W4[tid];
            #pragma unroll
            for (int off = 32; off >= 1; off >>= 1) p += __shfl_xor(p, off, 64);
            if (tid == 0) {
                float o = lrelu_(p + b4[0]);
                out[myb * KAHEAD + kk] = o;
                cstore1(xw + (long)myb * RSTRIDE + XSLOT, o);
            }
        }
        if (kk < KAHEAD - 1) {
            gbar(bar, &epoch);
            float hp = 0.f;
            if (tid < 512) hp = cload1(dw + (long)(g * 32 + rowE) * RSTRIDE + jmapE);
            stagePanel(gPanelD, xhi, xlo, tid);
            __syncthreads();
            gemmA32(smem, waH, waL, cix, g, tid, ghs, lhw, bh, b_hh, false);
            __syncthreads();
            stagePanel(gPanelX, xhi, xlo, tid);
            __syncthreads();
            gemmC32(smem, wcH, wcL, cix, tid, gis, b_ih);
            __syncthreads();
            if (tid < 512) {
                float gr  = gis[rowE * 17 + jE]        + ghs[rowE * 17 + jE];
                float gz  = gis[544 + rowE * 17 + jE]  + ghs[544 + rowE * 17 + jE];
                float gni = gis[1088 + rowE * 17 + jE];
                float gnh = ghs[1088 + rowE * 17 + jE];
                float rg = fsig_(gr);
                float zg = fsig_(gz);
                float ng = ftanh_(gni + rg * gnh);
                cstore1(dw + (long)(g * 32 + rowE) * RSTRIDE + jmapE, (1.f - zg) * ng + zg * hp);
            }
            gbar(bar, &epoch);
        }
    }
}

// ---------------- host ----------------
extern "C" void kernel_launch(void* const* d_in, const int* in_sizes, int n_in,
                              void* d_out, int out_size, void* d_ws, size_t ws_size,
                              hipStream_t stream) {
    const float* hiddens = (const float*)d_in[0];
    const float* allys   = (const float*)d_in[1];
    const float* Wh   = (const float*)d_in[3];
    const float* bh   = (const float*)d_in[4];
    const float* Ws   = (const float*)d_in[5];
    const float* bs   = (const float*)d_in[6];
    const float* Wo   = (const float*)d_in[7];
    const float* bo   = (const float*)d_in[8];
    const float* W_ih = (const float*)d_in[9];
    const float* W_hh = (const float*)d_in[10];
    const float* b_ih = (const float*)d_in[11];
    const float* b_hh = (const float*)d_in[12];
    const float* W1 = (const float*)d_in[13];
    const float* b1 = (const float*)d_in[14];
    const float* W2 = (const float*)d_in[15];
    const float* b2 = (const float*)d_in[16];
    const float* W3 = (const float*)d_in[17];
    const float* b3 = (const float*)d_in[18];
    const float* W4 = (const float*)d_in[19];
    const float* b4 = (const float*)d_in[20];
    float* wsf = (float*)d_ws;
    float* outf = (float*)d_out;

    if (ws_size < (size_t)WS_FLOATS * sizeof(float)) {
        fprintf(stderr, "kernel_launch: workspace too small (%zu < %zu)\n",
                ws_size, (size_t)WS_FLOATS * sizeof(float));
        return;
    }

    prep_kernel<<<dim3(2048), dim3(256), 0, stream>>>(W_hh, W_ih, Wh, Ws, wsf);

    (void)hipFuncSetAttribute((const void*)fused_kernel,
                              hipFuncAttributeMaxDynamicSharedMemorySize, LDS_BYTES);

    void* args[] = { &hiddens, &allys, &bs, &Wo, &bo, &bh,
                     &b_ih, &b_hh, &W1, &b1, &W2, &b2, &W3, &b3, &W4, &b4,
                     &wsf, &outf };
    hipError_t e = hipLaunchCooperativeKernel((void*)fused_kernel,
                                              dim3(NBLOCKS), dim3(NTHREADS),
                                              args, LDS_BYTES, stream);
    if (e != hipSuccess) {
        fprintf(stderr, "coop launch failed (%d); plain fallback\n", (int)e);
        (void)hipGetLastError();
        fused_kernel<<<dim3(NBLOCKS), dim3(NTHREADS), LDS_BYTES, stream>>>(
            hiddens, allys, bs, Wo, bo, bh, b_ih, b_hh,
            W1, b1, W2, b2, W3, b3, W4, b4, wsf, outf);
    }
}

// Round 6
// 2209.466 us; speedup vs baseline: 2.1005x; 2.1005x over previous
//
#include <hip/hip_runtime.h>
#include <cstdio>

#ifndef __has_builtin
#define __has_builtin(x) 0
#endif

// ---------------- problem constants ----------------
#define NB      256
#define NT      48
#define NS      512
#define KAHEAD  4
#define NTHREADS 1024
#define NBLOCKS  256
#define GSIZE    32
#define RSTRIDE  544     // exchange row floats (512 d / 513 x used, rest zero)
#define XSLOT    512     // x scalar slot
#define PANELF   17408   // 32*544 floats per group panel
#define XROWB    1088    // LDS f16 panel row stride bytes (544 halfs)

// ---------------- workspace (float offsets) ----------------
#define WS_D     0              // [256][544] d exchange fp32
#define WS_X     139264         // [256][544] x exchange
#define WS_LH    278528         // [256][512] lh exchange
#define WS_BAR   409600         // 256 uints
#define WS_WA    409856         // f16 [32 cix][2 w][32 kt][512]  = 1048576 halfs
#define WS_WC    934144         // f16 [32 cix][33 kt][512]       = 540672 halfs
#define WS_WN    1204480        // f16 [32 cix][17 kt][512]       = 278528 halfs
#define WS_WS    1343744        // f16 [32 nt][16 kt][512]        = 262144 halfs
#define WS_FLOATS 1474816       // 5.9 MB

// ---------------- LDS (byte offsets), total 147216 ----------------
#define L_XHI    0              // f16 panel hi [32][1088B] 34816
#define L_XLO    34816
#define L_LSB    69632          // ushort [48][512] bf16 ls 49152
#define L_GH     118784         // float [3][32][17]
#define L_GI     125312
#define L_LH     131840
#define L_WO     133888
#define L_E      135936
#define L_ATT    136192
#define L_CP     136448
#define L_H1P    138496
#define L_H1S    142592
#define L_H2P    143616
#define L_H2S    145664
#define L_H3P    146176
#define L_MISC   147200
#define LDS_BYTES 147216

typedef float    f4v  __attribute__((ext_vector_type(4)));
typedef float    f16v __attribute__((ext_vector_type(16)));
typedef _Float16 h4v  __attribute__((ext_vector_type(4)));
typedef _Float16 h8v  __attribute__((ext_vector_type(8)));

// ---------------- MFMA (f16, gfx950-listed builtins) ----------------
__device__ __forceinline__ f16v MFMA32(h8v a, h8v b, f16v c) {
    return __builtin_amdgcn_mfma_f32_32x32x16_f16(a, b, c, 0, 0, 0);
}
__device__ __forceinline__ f4v MFMA16(h8v a, h8v b, f4v c) {
    return __builtin_amdgcn_mfma_f32_16x16x32_f16(a, b, c, 0, 0, 0);
}

// ---------------- math ----------------
__device__ __forceinline__ float frcp_(float x) {
#if __has_builtin(__builtin_amdgcn_rcpf)
    return __builtin_amdgcn_rcpf(x);
#else
    return 1.0f / x;
#endif
}
__device__ __forceinline__ float ftanh_(float x) {
    float e = __expf(2.0f * x);
    return 1.0f - 2.0f * frcp_(e + 1.0f);
}
__device__ __forceinline__ float fsig_(float x) { return frcp_(1.0f + __expf(-x)); }
__device__ __forceinline__ float lrelu_(float x) { return fmaxf(x, 0.01f * x); }
__device__ __forceinline__ unsigned short rne16_(unsigned u) {
    return (unsigned short)((u + 0x7FFFu + ((u >> 16) & 1u)) >> 16);
}
__device__ __forceinline__ float bf2f_(unsigned short b) {
    return __uint_as_float(((unsigned)b) << 16);
}
__device__ __forceinline__ void split16_(float v, _Float16& hi, _Float16& lo) {
    _Float16 h = (_Float16)v;
    hi = h;
    lo = (_Float16)(v - (float)h);
}

// ---------------- XCD-local (L2-scope) coherent access: sc0 (r5-proven) ----------------
__device__ __forceinline__ void cstore1(float* p, float v) {
    asm volatile("global_store_dword %0, %1, off sc0" :: "v"(p), "v"(v) : "memory");
}
__device__ __forceinline__ f4v cload4(const float* p) {
    f4v v;
    asm volatile("global_load_dwordx4 %0, %1, off sc0" : "=v"(v) : "v"(p));
    return v;
}
__device__ __forceinline__ float cload1(const float* p) {
    float v;
    asm volatile("global_load_dword %0, %1, off sc0" : "=v"(v) : "v"(p));
    return v;
}
__device__ __forceinline__ void cwait() {
    asm volatile("s_waitcnt vmcnt(0)" ::: "memory");
    __builtin_amdgcn_sched_barrier(0);
}

// Group barrier (agent-scope counter; r2-r5 proven). Guard tightened to cap a
// broken replay at ~10ms (r5 outlier = 2 guard timeouts at 1<<22).
__device__ __forceinline__ void gbar(unsigned* bar, unsigned* epoch) {
    asm volatile("s_waitcnt vmcnt(0)" ::: "memory");
    __syncthreads();
    if (threadIdx.x == 0) {
        *epoch += GSIZE;
        __hip_atomic_fetch_add(bar, 1u, __ATOMIC_RELAXED, __HIP_MEMORY_SCOPE_AGENT);
        unsigned target = *epoch;
        int guard = 0;
        while (__hip_atomic_load(bar, __ATOMIC_RELAXED, __HIP_MEMORY_SCOPE_AGENT) < target) {
#if __has_builtin(__builtin_amdgcn_s_sleep)
            __builtin_amdgcn_s_sleep(2);
#endif
            if (++guard > (1 << 16)) break;
        }
    }
    __syncthreads();
}

// ---------------- staging: fp32 exchange panel -> LDS f16 hi/lo ----------------
__device__ __forceinline__ void cvtStore_(char* hiB, char* loB, int idx, f4v v) {
    unsigned row = (unsigned)idx / 544u;
    unsigned col = (unsigned)idx - row * 544u;
    h4v h, l;
    #pragma unroll
    for (int i = 0; i < 4; ++i) { _Float16 hh, ll; split16_(v[i], hh, ll); h[i] = hh; l[i] = ll; }
    *(h4v*)(hiB + row * XROWB + col * 2) = h;
    *(h4v*)(loB + row * XROWB + col * 2) = l;
}
__device__ __forceinline__ void stagePanel(const float* __restrict__ gsrc,
                                           char* __restrict__ hiB,
                                           char* __restrict__ loB, int tid) {
    f4v v0 = cload4(gsrc + tid * 4);
    f4v v1 = cload4(gsrc + 4096 + tid * 4);
    f4v v2 = cload4(gsrc + 8192 + tid * 4);
    f4v v3 = cload4(gsrc + 12288 + tid * 4);
    f4v v4 = {0.f, 0.f, 0.f, 0.f};
    if (tid < 256) v4 = cload4(gsrc + 16384 + tid * 4);
    cwait();
    cvtStore_(hiB, loB, tid * 4, v0);
    cvtStore_(hiB, loB, 4096 + tid * 4, v1);
    cvtStore_(hiB, loB, 8192 + tid * 4, v2);
    cvtStore_(hiB, loB, 12288 + tid * 4, v3);
    if (tid < 256) cvtStore_(hiB, loB, 16384 + tid * 4, v4);
}

// ---------------- GEMMs ----------------
// Stage A: C[32x64] = D[32x512] @ W (2 waves, 32x32x16_f16, A hi/lo 2-term)
__device__ __forceinline__ void gemmA(const char* smem, const _Float16* WA,
        int cix, int g, int tid, float* ghs, float* lhw,
        const float* bh, const float* bhh, bool doLH) {
    const int w = tid >> 6;
    if (w >= 2) return;
    const int l = tid & 63;
    const int aoff = (l & 31) * XROWB + ((l >> 5) << 4);
    const _Float16* Bp = WA + ((long)(cix * 2 + w) * 32) * 512 + (l << 3);
    f16v acc = {0,0,0,0,0,0,0,0,0,0,0,0,0,0,0,0};
    #pragma unroll 4
    for (int kt = 0; kt < 32; ++kt) {
        h8v ah = *(const h8v*)(smem + L_XHI + aoff + kt * 32);
        h8v al = *(const h8v*)(smem + L_XLO + aoff + kt * 32);
        h8v b  = *(const h8v*)(Bp + kt * 512);
        acc = MFMA32(ah, b, acc);
        acc = MFMA32(al, b, acc);
    }
    const int c = w * 32 + (l & 31);
    const int rb = (l >> 5) << 2;
    if (c < 16) {
        if (doLH) {
            const int j = cix * 16 + c;
            const float b = bh[j];
            #pragma unroll
            for (int r = 0; r < 16; ++r) {
                int row = (r & 3) + ((r >> 2) << 3) + rb;   // verified 32x32 C/D map
                cstore1(lhw + (long)(g * 32 + row) * NS + j, acc[r] + b);
            }
        }
    } else {
        const int gate = (c - 16) >> 4, jj = (c - 16) & 15;
        const float b = bhh[gate * 512 + cix * 16 + jj];
        #pragma unroll
        for (int r = 0; r < 16; ++r) {
            int row = (r & 3) + ((r >> 2) << 3) + rb;
            ghs[gate * 544 + row * 17 + jj] = acc[r] + b;
        }
    }
}

// Stage C r,z gates: 1 wave, 32 cols (c<16 -> r, else z), K=528 (33 kt)
__device__ __forceinline__ void gemmCrz(const char* smem, const _Float16* WC,
        int cix, int tid, float* gis, const float* bih) {
    if ((tid >> 6) != 0) return;
    const int l = tid & 63;
    const int aoff = (l & 31) * XROWB + ((l >> 5) << 4);
    const _Float16* Bp = WC + ((long)cix * 33) * 512 + (l << 3);
    f16v acc = {0,0,0,0,0,0,0,0,0,0,0,0,0,0,0,0};
    #pragma unroll 3
    for (int kt = 0; kt < 33; ++kt) {
        h8v ah = *(const h8v*)(smem + L_XHI + aoff + kt * 32);
        h8v al = *(const h8v*)(smem + L_XLO + aoff + kt * 32);
        h8v b  = *(const h8v*)(Bp + kt * 512);
        acc = MFMA32(ah, b, acc);
        acc = MFMA32(al, b, acc);
    }
    const int c = l & 31, gate = c >> 4, jj = c & 15;
    const int rb = (l >> 5) << 2;
    const float b = bih[gate * 512 + cix * 16 + jj];
    #pragma unroll
    for (int r = 0; r < 16; ++r) {
        int row = (r & 3) + ((r >> 2) << 3) + rb;
        gis[gate * 544 + row * 17 + jj] = acc[r] + b;
    }
}

// Stage C n gate: 1 wave, 16 cols, 16x16x32_f16, 2 M-subtiles, K=544 (17 kt)
__device__ __forceinline__ void gemmCn(const char* smem, const _Float16* WN,
        int cix, int tid, float* gis, const float* bih) {
    if ((tid >> 6) != 1) return;
    const int l = tid & 63;
    const _Float16* Bp = WN + ((long)cix * 17) * 512 + (l << 3);
    const int jj = l & 15;
    const float b = bih[2 * 512 + cix * 16 + jj];
    #pragma unroll
    for (int msub = 0; msub < 2; ++msub) {
        const int aoff = (msub * 16 + (l & 15)) * XROWB + ((l >> 4) << 4);
        f4v acc = {0.f, 0.f, 0.f, 0.f};
        #pragma unroll 4
        for (int kt = 0; kt < 17; ++kt) {
            h8v ah = *(const h8v*)(smem + L_XHI + aoff + kt * 64);
            h8v al = *(const h8v*)(smem + L_XLO + aoff + kt * 64);
            h8v bb = *(const h8v*)(Bp + kt * 512);
            acc = MFMA16(ah, bb, acc);
            acc = MFMA16(al, bb, acc);
        }
        #pragma unroll
        for (int r = 0; r < 4; ++r) {
            int row = msub * 16 + ((l >> 4) << 2) + r;   // verified 16x16 C/D map
            gis[2 * 544 + row * 17 + jj] = acc[r] + b;
        }
    }
}

// startup ls GEMM: 16 waves, 16x16x32_f16, K=512 (16 kt)
__device__ __forceinline__ void lsGemm(const char* smem, const _Float16* WS_,
        int tid, int ch, unsigned short* lsb, const float* bs) {
    const int w = tid >> 6, l = tid & 63;
    const int mt = w & 1, ng = w >> 1;
    const int aoff = (mt * 16 + (l & 15)) * XROWB + ((l >> 4) << 4);
    f4v acc[4] = {{0,0,0,0},{0,0,0,0},{0,0,0,0},{0,0,0,0}};
    for (int kt = 0; kt < 16; ++kt) {
        h8v ah = *(const h8v*)(smem + L_XHI + aoff + kt * 64);
        h8v al = *(const h8v*)(smem + L_XLO + aoff + kt * 64);
        #pragma unroll
        for (int i = 0; i < 4; ++i) {
            const _Float16* bp = WS_ + ((long)((ng * 4 + i) * 16 + kt)) * 512 + (l << 3);
            h8v bb = *(const h8v*)bp;
            acc[i] = MFMA16(ah, bb, acc[i]);
            acc[i] = MFMA16(al, bb, acc[i]);
        }
    }
    #pragma unroll
    for (int i = 0; i < 4; ++i) {
        const int n = (ng * 4 + i) * 16 + (l & 15);
        const float bsv = bs[n];
        #pragma unroll
        for (int r = 0; r < 4; ++r) {
            int row = mt * 16 + ((l >> 4) << 2) + r;
            if (row < 24)
                lsb[(ch * 24 + row) * NS + n] = rne16_(__float_as_uint(acc[i][r] + bsv));
        }
    }
}

// ---------------- prep: f16 fragment packing + zeroing ----------------
__global__ void prep_kernel(const float* __restrict__ Whh,
                            const float* __restrict__ Wih,
                            const float* __restrict__ Wh,
                            const float* __restrict__ Ws,
                            float* __restrict__ ws) {
    long i = (long)blockIdx.x * blockDim.x + threadIdx.x;
    long stride = (long)gridDim.x * blockDim.x;
    _Float16* wa = (_Float16*)(ws + WS_WA);
    _Float16* wc = (_Float16*)(ws + WS_WC);
    _Float16* wn = (_Float16*)(ws + WS_WN);
    _Float16* wsls = (_Float16*)(ws + WS_WS);

    // gemmA: p = ((cix*2+w)*32 + kt)*64 + l
    for (long p = i; p < 131072; p += stride) {
        int l = (int)(p & 63);
        long t = p >> 6;
        int kt = (int)(t & 31);
        int u = (int)(t >> 5);
        int w = u & 1, cix = u >> 1;
        int c = w * 32 + (l & 31);
        #pragma unroll
        for (int e = 0; e < 8; ++e) {
            int k = kt * 16 + ((l >> 5) << 3) + e;
            float wv;
            if (c < 16) wv = Wh[(long)k * 512 + cix * 16 + c];
            else {
                int gate = (c - 16) >> 4, j = cix * 16 + ((c - 16) & 15);
                wv = Whh[((long)(gate * 512 + j)) * 512 + k];
            }
            wa[p * 8 + e] = (_Float16)wv;
        }
    }
    // gemmC rz: p = (cix*33 + kt)*64 + l
    for (long p = i; p < 67584; p += stride) {
        int l = (int)(p & 63);
        long t = p >> 6;
        int kt = (int)(t % 33), cix = (int)(t / 33);
        int c = l & 31, gate = c >> 4, j = cix * 16 + (c & 15);
        #pragma unroll
        for (int e = 0; e < 8; ++e) {
            int k = kt * 16 + ((l >> 5) << 3) + e;
            float wv = (k <= 512) ? Wih[((long)(gate * 512 + j)) * 513 + k] : 0.f;
            wc[p * 8 + e] = (_Float16)wv;
        }
    }
    // gemmC n: p = (cix*17 + kt)*64 + l
    for (long p = i; p < 34816; p += stride) {
        int l = (int)(p & 63);
        long t = p >> 6;
        int kt = (int)(t % 17), cix = (int)(t / 17);
        int j = cix * 16 + (l & 15);
        #pragma unroll
        for (int e = 0; e < 8; ++e) {
            int k = kt * 32 + ((l >> 4) << 3) + e;
            float wv = (k <= 512) ? Wih[((long)(1024 + j)) * 513 + k] : 0.f;
            wn[p * 8 + e] = (_Float16)wv;
        }
    }
    // ls: p = (nt*16 + kt)*64 + l
    for (long p = i; p < 32768; p += stride) {
        int l = (int)(p & 63);
        long t = p >> 6;
        int kt = (int)(t & 15), nt = (int)(t >> 4);
        int n = nt * 16 + (l & 15);
        #pragma unroll
        for (int e = 0; e < 8; ++e) {
            int k = kt * 32 + ((l >> 4) << 3) + e;
            wsls[p * 8 + e] = (_Float16)Ws[(long)k * 512 + n];
        }
    }
    for (long p = i; p < 278528; p += stride) ws[WS_D + p] = 0.0f;   // d+x (pads stay 0)
    if (i < 256) ((unsigned*)(ws + WS_BAR))[i] = 0u;
}

// ---------------- main persistent cooperative kernel ----------------
__global__ void __launch_bounds__(NTHREADS, 4) fused_kernel(
        const float* __restrict__ hiddens, const float* __restrict__ allys,
        const float* __restrict__ bs,
        const float* __restrict__ Wo, const float* __restrict__ bo,
        const float* __restrict__ bh,
        const float* __restrict__ b_ih, const float* __restrict__ b_hh,
        const float* __restrict__ W1, const float* __restrict__ b1,
        const float* __restrict__ W2, const float* __restrict__ b2,
        const float* __restrict__ W3, const float* __restrict__ b3,
        const float* __restrict__ W4, const float* __restrict__ b4,
        float* __restrict__ ws, float* __restrict__ out) {
    const int tid = threadIdx.x;

    float* dw  = ws + WS_D;
    float* xw  = ws + WS_X;
    float* lhw = ws + WS_LH;
    const _Float16* waF = (const _Float16*)(ws + WS_WA);
    const _Float16* wcF = (const _Float16*)(ws + WS_WC);
    const _Float16* wnF = (const _Float16*)(ws + WS_WN);
    const _Float16* wsF = (const _Float16*)(ws + WS_WS);
    unsigned* barbase = (unsigned*)(ws + WS_BAR);

    extern __shared__ char smem[];
    char*           xhi   = smem + L_XHI;
    char*           xlo   = smem + L_XLO;
    unsigned short* lsb   = (unsigned short*)(smem + L_LSB);
    float*          ghs   = (float*)(smem + L_GH);
    float*          gis   = (float*)(smem + L_GI);
    float*          lh_s  = (float*)(smem + L_LH);
    float*          wo_s  = (float*)(smem + L_WO);
    float*          e_s   = (float*)(smem + L_E);
    float*          att_s = (float*)(smem + L_ATT);
    float*          cp_s  = (float*)(smem + L_CP);
    float*          h1p   = (float*)(smem + L_H1P);
    float*          h1s   = (float*)(smem + L_H1S);
    float*          h2p   = (float*)(smem + L_H2P);
    float*          h2s   = (float*)(smem + L_H2S);
    float*          h3p   = (float*)(smem + L_H3P);
    int*            misc  = (int*)(smem + L_MISC);

    // ---- dynamic XCD-local grouping (149KB LDS forces 1 block/CU -> 32/XCD) ----
    if (tid == 0) {
        unsigned xcc;
        asm volatile("s_getreg_b32 %0, hwreg(HW_REG_XCC_ID)" : "=s"(xcc));
        int gx = (int)(xcc & 7u);
        unsigned rk = __hip_atomic_fetch_add(barbase + gx * 32 + 1, 1u,
                                             __ATOMIC_RELAXED, __HIP_MEMORY_SCOPE_AGENT);
        misc[0] = gx;
        misc[1] = (int)(rk & 31u);
    }
    __syncthreads();
    const int g = misc[0], cix = misc[1];
    const int myb = g * 32 + cix;
    unsigned* bar = barbase + (g << 5);
    unsigned epoch = 0;

    const int sS = tid & 511, th = tid >> 9;
    const int rowE = tid >> 4, jE = tid & 15;          // gate-epilogue map (tid<512)
    const int jgE = cix * 16 + jE;
    const float* gPanelD = dw + (long)g * GSIZE * RSTRIDE;
    const float* gPanelX = xw + (long)g * GSIZE * RSTRIDE;

    float hreg[24];
    if (tid < NS) wo_s[tid] = Wo[tid];
    #pragma unroll
    for (int q = 0; q < 24; ++q)
        hreg[q] = hiddens[((long)myb * NT + th * 24 + q) * NS + sS];

    // ==== startup: zero panels, then ls = hiddens@Ws + bs via f16 MFMA ====
    for (int i = tid; i < 4352; i += NTHREADS) *(f4v*)(smem + i * 16) = (f4v){0,0,0,0};
    for (int ch = 0; ch < 2; ++ch) {
        __syncthreads();
        {   // stage 24 fp32 rows -> f16 hi/lo panels rows 0..23 (cols 0..511)
            const float* src = hiddens + ((long)myb * NT + ch * 24) * NS;
            const int i0 = tid * 12;
            #pragma unroll
            for (int j3 = 0; j3 < 3; ++j3) {
                int idx = i0 + j3 * 4;
                f4v v = *(const f4v*)(src + idx);
                int row = idx >> 9, col = idx & 511;
                h4v h, l;
                #pragma unroll
                for (int e = 0; e < 4; ++e) { _Float16 hh, ll; split16_(v[e], hh, ll); h[e] = hh; l[e] = ll; }
                *(h4v*)(xhi + row * XROWB + col * 2) = h;
                *(h4v*)(xlo + row * XROWB + col * 2) = l;
            }
        }
        __syncthreads();
        lsGemm(smem, wsF, tid, ch, lsb, bs);
    }
    __syncthreads();

    const float bo0 = bo[0];

    // ================= time scan: 3 group barriers per step =================
    for (int t = 0; t < NT; ++t) {
        // ---- A: stage d -> panels; MFMA gh + lh ----
        stagePanel(gPanelD, xhi, xlo, tid);
        __syncthreads();
        gemmA(smem, waF, cix, g, tid, ghs, lhw, bh, b_hh, true);
        gbar(bar, &epoch);

        // ---- B: attention for own row ----
        if (tid < 128) {
            f4v v = cload4(lhw + (long)myb * NS + tid * 4);
            cwait();
            *(f4v*)(lh_s + tid * 4) = v;
        }
        if (tid == 0) cstore1(xw + (long)myb * RSTRIDE + XSLOT, allys[myb * NT + t]);
        __syncthreads();
        {
            const int wv = tid >> 6, ln = tid & 63;
            for (int q = 0; q < 3; ++q) {
                const int tt = wv * 3 + q;
                float p = 0.f;
                #pragma unroll
                for (int i2 = 0; i2 < 8; ++i2) {
                    int s = ln + (i2 << 6);
                    p = fmaf(wo_s[s], ftanh_(lh_s[s] + bf2f_(lsb[tt * NS + s])), p);
                }
                #pragma unroll
                for (int off = 32; off >= 1; off >>= 1) p += __shfl_xor(p, off, 64);
                if (ln == 0) e_s[tt] = p + bo0;
            }
        }
        __syncthreads();
        if (tid < 64) {
            float v = (tid < NT) ? e_s[tid] : -1e30f;
            float m = v;
            #pragma unroll
            for (int off = 32; off >= 1; off >>= 1) m = fmaxf(m, __shfl_xor(m, off, 64));
            float ex = (tid < NT) ? __expf(v - m) : 0.0f;
            float ssum = ex;
            #pragma unroll
            for (int off = 32; off >= 1; off >>= 1) ssum += __shfl_xor(ssum, off, 64);
            if (tid < NT) att_s[tid] = ex * frcp_(ssum);
        }
        __syncthreads();
        {
            float p = 0.f;
            #pragma unroll
            for (int q = 0; q < 24; ++q) p = fmaf(att_s[th * 24 + q], hreg[q], p);
            if (th == 0) cp_s[sS] = p;
            __syncthreads();
            if (th == 1) cstore1(xw + (long)myb * RSTRIDE + sS, p + cp_s[sS]);
        }
        gbar(bar, &epoch);

        // ---- C: stage x -> panels; MFMA gi; GRU gates ----
        float hp = 0.f;
        if (tid < 512) hp = cload1(dw + (long)(g * 32 + rowE) * RSTRIDE + jgE);
        stagePanel(gPanelX, xhi, xlo, tid);
        __syncthreads();
        gemmCrz(smem, wcF, cix, tid, gis, b_ih);
        gemmCn(smem, wnF, cix, tid, gis, b_ih);
        __syncthreads();
        if (tid < 512) {
            float gr  = gis[rowE * 17 + jE]        + ghs[rowE * 17 + jE];
            float gz  = gis[544 + rowE * 17 + jE]  + ghs[544 + rowE * 17 + jE];
            float gni = gis[1088 + rowE * 17 + jE];
            float gnh = ghs[1088 + rowE * 17 + jE];
            float rg = fsig_(gr);
            float zg = fsig_(gz);
            float ng = ftanh_(gni + rg * gnh);
            cstore1(dw + (long)(g * 32 + rowE) * RSTRIDE + jgE, (1.f - zg) * ng + zg * hp);
        }
        gbar(bar, &epoch);
    }

    // ================= k_wk_ahead head =================
    for (int kk = 0; kk < KAHEAD; ++kk) {
        {
            float v = 0.f;
            if (tid < NS) v = cload1(dw + (long)myb * RSTRIDE + tid);
            cwait();
            if (tid < NS) lh_s[tid] = v;
        }
        __syncthreads();
        {   // M1: 512 -> 256
            int n = tid & 255, q4 = tid >> 8;
            const float* av = lh_s + q4 * 128;
            const float* wp = W1 + (long)(q4 * 128) * 256 + n;
            float acc = 0.f;
            #pragma unroll 4
            for (int k2 = 0; k2 < 128; ++k2) { acc = fmaf(av[k2], wp[0], acc); wp += 256; }
            h1p[n * 4 + q4] = acc;
        }
        __syncthreads();
        if (tid < 256) {
            float v = h1p[tid * 4] + h1p[tid * 4 + 1] + h1p[tid * 4 + 2] + h1p[tid * 4 + 3];
            h1s[tid] = lrelu_(v + b1[tid]);
        }
        __syncthreads();
        if (tid < 512) {   // M2: 256 -> 128
            int n = tid & 127, q4 = tid >> 7;
            const float* av = h1s + q4 * 64;
            const float* wp = W2 + (long)(q4 * 64) * 128 + n;
            float acc = 0.f;
            #pragma unroll 4
            for (int k2 = 0; k2 < 64; ++k2) { acc = fmaf(av[k2], wp[0], acc); wp += 128; }
            h2p[n * 4 + q4] = acc;
        }
        __syncthreads();
        if (tid < 128) {
            float v = h2p[tid * 4] + h2p[tid * 4 + 1] + h2p[tid * 4 + 2] + h2p[tid * 4 + 3];
            h2s[tid] = lrelu_(v + b2[tid]);
        }
        __syncthreads();
        if (tid < 256) {   // M3: 128 -> 64
            int n = tid & 63, q4 = tid >> 6;
            const float* av = h2s + q4 * 32;
            const float* wp = W3 + (long)(q4 * 32) * 64 + n;
            float acc = 0.f;
            #pragma unroll 4
            for (int k2 = 0; k2 < 32; ++k2) { acc = fmaf(av[k2], wp[0], acc); wp += 64; }
            h3p[n * 4 + q4] = acc;
        }
        __syncthreads();
        if (tid < 64) {    // M3 epilogue + M4
            float v = h3p[tid * 4] + h3p[tid * 4 + 1] + h3p[tid * 4 + 2] + h3p[tid * 4 + 3];
            float h3v = lrelu_(v + b3[tid]);
            float p = h3v * W4[tid];
            #pragma unroll
            for (int off = 32; off >= 1; off >>= 1) p += __shfl_xor(p, off, 64);
            if (tid == 0) {
                float o = lrelu_(p + b4[0]);
                out[myb * KAHEAD + kk] = o;
                cstore1(xw + (long)myb * RSTRIDE + XSLOT, o);
            }
        }
        if (kk < KAHEAD - 1) {
            gbar(bar, &epoch);
            float hp = 0.f;
            if (tid < 512) hp = cload1(dw + (long)(g * 32 + rowE) * RSTRIDE + jgE);
            stagePanel(gPanelD, xhi, xlo, tid);
            __syncthreads();
            gemmA(smem, waF, cix, g, tid, ghs, lhw, bh, b_hh, false);
            __syncthreads();
            stagePanel(gPanelX, xhi, xlo, tid);
            __syncthreads();
            gemmCrz(smem, wcF, cix, tid, gis, b_ih);
            gemmCn(smem, wnF, cix, tid, gis, b_ih);
            __syncthreads();
            if (tid < 512) {
                float gr  = gis[rowE * 17 + jE]        + ghs[rowE * 17 + jE];
                float gz  = gis[544 + rowE * 17 + jE]  + ghs[544 + rowE * 17 + jE];
                float gni = gis[1088 + rowE * 17 + jE];
                float gnh = ghs[1088 + rowE * 17 + jE];
                float rg = fsig_(gr);
                float zg = fsig_(gz);
                float ng = ftanh_(gni + rg * gnh);
                cstore1(dw + (long)(g * 32 + rowE) * RSTRIDE + jgE, (1.f - zg) * ng + zg * hp);
            }
            gbar(bar, &epoch);
        }
    }
}

// ---------------- host ----------------
extern "C" void kernel_launch(void* const* d_in, const int* in_sizes, int n_in,
                              void* d_out, int out_size, void* d_ws, size_t ws_size,
                              hipStream_t stream) {
    const float* hiddens = (const float*)d_in[0];
    const float* allys   = (const float*)d_in[1];
    const float* Wh   = (const float*)d_in[3];
    const float* bh   = (const float*)d_in[4];
    const float* Ws   = (const float*)d_in[5];
    const float* bs   = (const float*)d_in[6];
    const float* Wo   = (const float*)d_in[7];
    const float* bo   = (const float*)d_in[8];
    const float* W_ih = (const float*)d_in[9];
    const float* W_hh = (const float*)d_in[10];
    const float* b_ih = (const float*)d_in[11];
    const float* b_hh = (const float*)d_in[12];
    const float* W1 = (const float*)d_in[13];
    const float* b1 = (const float*)d_in[14];
    const float* W2 = (const float*)d_in[15];
    const float* b2 = (const float*)d_in[16];
    const float* W3 = (const float*)d_in[17];
    const float* b3 = (const float*)d_in[18];
    const float* W4 = (const float*)d_in[19];
    const float* b4 = (const float*)d_in[20];
    float* wsf = (float*)d_ws;
    float* outf = (float*)d_out;

    if (ws_size < (size_t)WS_FLOATS * sizeof(float)) {
        fprintf(stderr, "kernel_launch: workspace too small (%zu < %zu)\n",
                ws_size, (size_t)WS_FLOATS * sizeof(float));
        return;
    }

    prep_kernel<<<dim3(2048), dim3(256), 0, stream>>>(W_hh, W_ih, Wh, Ws, wsf);

    (void)hipFuncSetAttribute((const void*)fused_kernel,
                              hipFuncAttributeMaxDynamicSharedMemorySize, LDS_BYTES);

    void* args[] = { &hiddens, &allys, &bs, &Wo, &bo, &bh,
                     &b_ih, &b_hh, &W1, &b1, &W2, &b2, &W3, &b3, &W4, &b4,
                     &wsf, &outf };
    hipError_t e = hipLaunchCooperativeKernel((void*)fused_kernel,
                                              dim3(NBLOCKS), dim3(NTHREADS),
                                              args, LDS_BYTES, stream);
    if (e != hipSuccess) {
        fprintf(stderr, "coop launch failed (%d); plain fallback\n", (int)e);
        (void)hipGetLastError();
        fused_kernel<<<dim3(NBLOCKS), dim3(NTHREADS), LDS_BYTES, stream>>>(
            hiddens, allys, bs, Wo, bo, bh, b_ih, b_hh,
            W1, b1, W2, b2, W3, b3, W4, b4, wsf, outf);
    }
}

// Round 7
// 2017.610 us; speedup vs baseline: 2.3002x; 1.0951x over previous
//
#include <hip/hip_runtime.h>
#include <cstdio>

#ifndef __has_builtin
#define __has_builtin(x) 0
#endif

// ---------------- problem constants ----------------
#define NB      256
#define NT      48
#define NS      512
#define KAHEAD  4
#define NTHREADS 1024
#define NBLOCKS  256
#define GSIZE    32
#define RSTRIDE  544     // exchange row floats (512 d / 513 x used)
#define XSLOT    512     // x scalar slot
#define XROWB    1088    // LDS f16 panel row stride bytes

// ---------------- workspace (float offsets) ----------------
#define WS_D     0              // [256][544] d exchange fp32
#define WS_X     139264         // [256][544] x exchange
#define WS_LH    278528         // [256][512] lh exchange
#define WS_BAR   409600         // 256 uints
#define WS_WA    409856         // f16 [32 cix][2 nt][32 kt][512]
#define WS_WC    934144         // f16 [32 cix][32 kt][512]
#define WS_WN    1196288        // f16 [32 cix][16 kt][512]
#define WS_WS    1327360        // f16 [32 nt][16 kt][512]
#define WS_FLOATS 1458432       // 5.83 MB

// ---------------- LDS (byte offsets), total 155408 ----------------
#define L_XHI    0              // f16 panel hi [32][1088B] 34816
#define L_XLO    34816
#define L_LSB    69632          // ushort [48][512] bf16 ls 49152
#define L_GH     118784         // float [3][32][17]
#define L_GI     125312
#define L_LH     131840
#define L_WO     133888
#define L_E      135936
#define L_ATT    136192
#define L_CP     136448
#define L_H1P    138496
#define L_H1S    142592
#define L_H2P    143616
#define L_H2S    145664
#define L_H3P    146176
#define L_MISC   147200
#define L_PB     147216         // float[2048] K-split partial buffer (8KB)
#define LDS_BYTES 155408

typedef float    f4v  __attribute__((ext_vector_type(4)));
typedef float    f16v __attribute__((ext_vector_type(16)));
typedef _Float16 h4v  __attribute__((ext_vector_type(4)));
typedef _Float16 h8v  __attribute__((ext_vector_type(8)));

// ---------------- MFMA (f16) ----------------
__device__ __forceinline__ f16v MFMA32(h8v a, h8v b, f16v c) {
    return __builtin_amdgcn_mfma_f32_32x32x16_f16(a, b, c, 0, 0, 0);
}
__device__ __forceinline__ f4v MFMA16(h8v a, h8v b, f4v c) {
    return __builtin_amdgcn_mfma_f32_16x16x32_f16(a, b, c, 0, 0, 0);
}

// ---------------- math ----------------
__device__ __forceinline__ float frcp_(float x) {
#if __has_builtin(__builtin_amdgcn_rcpf)
    return __builtin_amdgcn_rcpf(x);
#else
    return 1.0f / x;
#endif
}
__device__ __forceinline__ float ftanh_(float x) {
    float e = __expf(2.0f * x);
    return 1.0f - 2.0f * frcp_(e + 1.0f);
}
__device__ __forceinline__ float fsig_(float x) { return frcp_(1.0f + __expf(-x)); }
__device__ __forceinline__ float lrelu_(float x) { return fmaxf(x, 0.01f * x); }
__device__ __forceinline__ unsigned short rne16_(unsigned u) {
    return (unsigned short)((u + 0x7FFFu + ((u >> 16) & 1u)) >> 16);
}
__device__ __forceinline__ float bf2f_(unsigned short b) {
    return __uint_as_float(((unsigned)b) << 16);
}
__device__ __forceinline__ void split16_(float v, _Float16& hi, _Float16& lo) {
    _Float16 h = (_Float16)v;
    hi = h;
    lo = (_Float16)(v - (float)h);
}

// ---------------- XCD-local (L2-scope) coherent access: sc0; nt = evict-first ----------------
__device__ __forceinline__ void cstore1(float* p, float v) {
    asm volatile("global_store_dword %0, %1, off sc0 nt" :: "v"(p), "v"(v) : "memory");
}
__device__ __forceinline__ f4v cload4(const float* p) {
    f4v v;
    asm volatile("global_load_dwordx4 %0, %1, off sc0" : "=v"(v) : "v"(p));
    return v;
}
__device__ __forceinline__ float cload1(const float* p) {
    float v;
    asm volatile("global_load_dword %0, %1, off sc0" : "=v"(v) : "v"(p));
    return v;
}
__device__ __forceinline__ void cwait() {
    asm volatile("s_waitcnt vmcnt(0)" ::: "memory");
    __builtin_amdgcn_sched_barrier(0);
}

// Group barrier (agent-scope counter; r2-r6 proven).
__device__ __forceinline__ void gbar(unsigned* bar, unsigned* epoch) {
    asm volatile("s_waitcnt vmcnt(0)" ::: "memory");
    __syncthreads();
    if (threadIdx.x == 0) {
        *epoch += GSIZE;
        __hip_atomic_fetch_add(bar, 1u, __ATOMIC_RELAXED, __HIP_MEMORY_SCOPE_AGENT);
        unsigned target = *epoch;
        int guard = 0;
        while (__hip_atomic_load(bar, __ATOMIC_RELAXED, __HIP_MEMORY_SCOPE_AGENT) < target) {
#if __has_builtin(__builtin_amdgcn_s_sleep)
            __builtin_amdgcn_s_sleep(2);
#endif
            if (++guard > (1 << 16)) break;
        }
    }
    __syncthreads();
}

// ---------------- staging: fp32 exchange panel -> LDS f16 hi/lo ----------------
__device__ __forceinline__ void cvtStore_(char* hiB, char* loB, int idx, f4v v) {
    unsigned row = (unsigned)idx / 544u;
    unsigned col = (unsigned)idx - row * 544u;
    h4v h, l;
    #pragma unroll
    for (int i = 0; i < 4; ++i) { _Float16 hh, ll; split16_(v[i], hh, ll); h[i] = hh; l[i] = ll; }
    *(h4v*)(hiB + row * XROWB + col * 2) = h;
    *(h4v*)(loB + row * XROWB + col * 2) = l;
}
__device__ __forceinline__ void stagePanel(const float* __restrict__ gsrc,
                                           char* __restrict__ hiB,
                                           char* __restrict__ loB, int tid) {
    f4v v0 = cload4(gsrc + tid * 4);
    f4v v1 = cload4(gsrc + 4096 + tid * 4);
    f4v v2 = cload4(gsrc + 8192 + tid * 4);
    f4v v3 = cload4(gsrc + 12288 + tid * 4);
    f4v v4 = {0.f, 0.f, 0.f, 0.f};
    if (tid < 256) v4 = cload4(gsrc + 16384 + tid * 4);
    cwait();
    cvtStore_(hiB, loB, tid * 4, v0);
    cvtStore_(hiB, loB, 4096 + tid * 4, v1);
    cvtStore_(hiB, loB, 8192 + tid * 4, v2);
    cvtStore_(hiB, loB, 12288 + tid * 4, v3);
    if (tid < 256) cvtStore_(hiB, loB, 16384 + tid * 4, v4);
}

// ---------------- GEMMs, K-split x2 across waves (internal barrier!) ----------------
// Stage A: C[32x64] = D[32x512] @ W ; waves 0..3 = (ntile, khalf)
__device__ __forceinline__ void gemmA(const char* smem, const _Float16* WA_,
        int cix, int g, int tid, float* ghs, float* lhw, float* pbuf,
        const float* bh, const float* bhh, bool doLH) {
    const int w = tid >> 6, l = tid & 63;
    const int nt2 = w & 1, kc = w >> 1;
    f16v acc = {0,0,0,0,0,0,0,0,0,0,0,0,0,0,0,0};
    if (w < 4) {
        const int aoff = (l & 31) * XROWB + ((l >> 5) << 4);
        const _Float16* Bp = WA_ + ((long)((cix * 2 + nt2) * 32 + kc * 16)) * 512 + (l << 3);
        #pragma unroll 4
        for (int kt = 0; kt < 16; ++kt) {
            h8v ah = *(const h8v*)(smem + L_XHI + aoff + (kc * 16 + kt) * 32);
            h8v al = *(const h8v*)(smem + L_XLO + aoff + (kc * 16 + kt) * 32);
            h8v b  = *(const h8v*)(Bp + kt * 512);
            acc = MFMA32(ah, b, acc);
            acc = MFMA32(al, b, acc);
        }
        if (kc == 1) {
            #pragma unroll
            for (int r = 0; r < 16; ++r) pbuf[nt2 * 1024 + r * 64 + l] = acc[r];
        }
    }
    __syncthreads();   // all threads reach (no early return above)
    if (w < 2) {       // kc==0 waves finalize
        #pragma unroll
        for (int r = 0; r < 16; ++r) acc[r] += pbuf[nt2 * 1024 + r * 64 + l];
        const int c = nt2 * 32 + (l & 31);
        const int rb = (l >> 5) << 2;
        if (c < 16) {
            if (doLH) {
                const int j = cix * 16 + c;
                const float b = bh[j];
                #pragma unroll
                for (int r = 0; r < 16; ++r) {
                    int row = (r & 3) + ((r >> 2) << 3) + rb;   // verified 32x32 C/D map
                    cstore1(lhw + (long)(g * 32 + row) * NS + j, acc[r] + b);
                }
            }
        } else {
            const int gate = (c - 16) >> 4, jj = (c - 16) & 15;
            const float b = bhh[gate * 512 + cix * 16 + jj];
            #pragma unroll
            for (int r = 0; r < 16; ++r) {
                int row = (r & 3) + ((r >> 2) << 3) + rb;
                ghs[gate * 544 + row * 17 + jj] = acc[r] + b;
            }
        }
    }
}

// Stage C: waves 0,1 = rz K-halves (32x32); waves 2,3 = n K-halves (16x16 x2 msub)
__device__ __forceinline__ void gemmC(const char* smem, const _Float16* WC_,
        const _Float16* WN_, int cix, int tid, float* gis, float* pbuf,
        const float* bih) {
    const int w = tid >> 6, l = tid & 63;
    f16v acc = {0,0,0,0,0,0,0,0,0,0,0,0,0,0,0,0};
    f4v an0 = {0.f,0.f,0.f,0.f}, an1 = {0.f,0.f,0.f,0.f};
    if (w < 2) {
        const int aoff = (l & 31) * XROWB + ((l >> 5) << 4);
        const _Float16* Bp = WC_ + ((long)(cix * 32 + w * 16)) * 512 + (l << 3);
        #pragma unroll 4
        for (int kt = 0; kt < 16; ++kt) {
            h8v ah = *(const h8v*)(smem + L_XHI + aoff + (w * 16 + kt) * 32);
            h8v al = *(const h8v*)(smem + L_XLO + aoff + (w * 16 + kt) * 32);
            h8v b  = *(const h8v*)(Bp + kt * 512);
            acc = MFMA32(ah, b, acc);
            acc = MFMA32(al, b, acc);
        }
        if (w == 1) {
            #pragma unroll
            for (int r = 0; r < 16; ++r) pbuf[r * 64 + l] = acc[r];
        }
    } else if (w < 4) {
        const int kc = w - 2;
        const _Float16* Bp = WN_ + ((long)(cix * 16 + kc * 8)) * 512 + (l << 3);
        const int a0 = (l & 15) * XROWB + ((l >> 4) << 4);
        const int a1 = (16 + (l & 15)) * XROWB + ((l >> 4) << 4);
        #pragma unroll 4
        for (int kt = 0; kt < 8; ++kt) {
            const int kb = (kc * 8 + kt) * 64;
            h8v b   = *(const h8v*)(Bp + kt * 512);
            h8v ah0 = *(const h8v*)(smem + L_XHI + a0 + kb);
            h8v al0 = *(const h8v*)(smem + L_XLO + a0 + kb);
            h8v ah1 = *(const h8v*)(smem + L_XHI + a1 + kb);
            h8v al1 = *(const h8v*)(smem + L_XLO + a1 + kb);
            an0 = MFMA16(ah0, b, an0); an0 = MFMA16(al0, b, an0);
            an1 = MFMA16(ah1, b, an1); an1 = MFMA16(al1, b, an1);
        }
        if (kc == 1) {
            #pragma unroll
            for (int r = 0; r < 4; ++r) {
                pbuf[1024 + r * 64 + l] = an0[r];
                pbuf[1280 + r * 64 + l] = an1[r];
            }
        }
    }
    __syncthreads();   // all threads reach
    if (w == 0) {
        #pragma unroll
        for (int r = 0; r < 16; ++r) acc[r] += pbuf[r * 64 + l];
        const int c = l & 31, gate = c >> 4, jj = c & 15;
        const int rb = (l >> 5) << 2;
        const float b = bih[gate * 512 + cix * 16 + jj];
        #pragma unroll
        for (int r = 0; r < 16; ++r) {
            int row = (r & 3) + ((r >> 2) << 3) + rb;
            gis[gate * 544 + row * 17 + jj] = acc[r] + b;
        }
    } else if (w == 2) {
        const int jj = l & 15;
        const float b = bih[1024 + cix * 16 + jj];
        #pragma unroll
        for (int r = 0; r < 4; ++r) {
            int row = ((l >> 4) << 2) + r;                      // verified 16x16 C/D map
            gis[1088 + row * 17 + jj] = an0[r] + pbuf[1024 + r * 64 + l] + b;
            gis[1088 + (16 + row) * 17 + jj] = an1[r] + pbuf[1280 + r * 64 + l] + b;
        }
    }
}

// startup ls GEMM: 16 waves, 16x16x32_f16, K=512
__device__ __forceinline__ void lsGemm(const char* smem, const _Float16* WS_,
        int tid, int ch, unsigned short* lsb, const float* bs) {
    const int w = tid >> 6, l = tid & 63;
    const int mt = w & 1, ng = w >> 1;
    const int aoff = (mt * 16 + (l & 15)) * XROWB + ((l >> 4) << 4);
    f4v acc[4] = {{0,0,0,0},{0,0,0,0},{0,0,0,0},{0,0,0,0}};
    for (int kt = 0; kt < 16; ++kt) {
        h8v ah = *(const h8v*)(smem + L_XHI + aoff + kt * 64);
        h8v al = *(const h8v*)(smem + L_XLO + aoff + kt * 64);
        #pragma unroll
        for (int i = 0; i < 4; ++i) {
            const _Float16* bp = WS_ + ((long)((ng * 4 + i) * 16 + kt)) * 512 + (l << 3);
            h8v bb = *(const h8v*)bp;
            acc[i] = MFMA16(ah, bb, acc[i]);
            acc[i] = MFMA16(al, bb, acc[i]);
        }
    }
    #pragma unroll
    for (int i = 0; i < 4; ++i) {
        const int n = (ng * 4 + i) * 16 + (l & 15);
        const float bsv = bs[n];
        #pragma unroll
        for (int r = 0; r < 4; ++r) {
            int row = mt * 16 + ((l >> 4) << 2) + r;
            if (row < 24)
                lsb[(ch * 24 + row) * NS + n] = rne16_(__float_as_uint(acc[i][r] + bsv));
        }
    }
}

// ---------------- prep: f16 fragment packing + zeroing ----------------
__global__ void prep_kernel(const float* __restrict__ Whh,
                            const float* __restrict__ Wih,
                            const float* __restrict__ Wh,
                            const float* __restrict__ Ws,
                            float* __restrict__ ws) {
    long i = (long)blockIdx.x * blockDim.x + threadIdx.x;
    long stride = (long)gridDim.x * blockDim.x;
    _Float16* wa = (_Float16*)(ws + WS_WA);
    _Float16* wc = (_Float16*)(ws + WS_WC);
    _Float16* wn = (_Float16*)(ws + WS_WN);
    _Float16* wsls = (_Float16*)(ws + WS_WS);

    // WA: p = ((cix*2+nt)*32 + kt)*64 + l
    for (long p = i; p < 131072; p += stride) {
        int l = (int)(p & 63);
        long t = p >> 6;
        int kt = (int)(t & 31);
        int u = (int)(t >> 5);
        int nt = u & 1, cix = u >> 1;
        int c = nt * 32 + (l & 31);
        #pragma unroll
        for (int e = 0; e < 8; ++e) {
            int k = kt * 16 + ((l >> 5) << 3) + e;
            float wv;
            if (c < 16) wv = Wh[(long)k * 512 + cix * 16 + c];
            else {
                int gate = (c - 16) >> 4, j = cix * 16 + ((c - 16) & 15);
                wv = Whh[((long)(gate * 512 + j)) * 512 + k];
            }
            wa[p * 8 + e] = (_Float16)wv;
        }
    }
    // WC: p = (cix*32 + kt)*64 + l  (K=512 exactly; scalar k=512 folded in epilogue)
    for (long p = i; p < 65536; p += stride) {
        int l = (int)(p & 63);
        long t = p >> 6;
        int kt = (int)(t & 31), cix = (int)(t >> 5);
        int c = l & 31, gate = c >> 4, j = cix * 16 + (c & 15);
        #pragma unroll
        for (int e = 0; e < 8; ++e) {
            int k = kt * 16 + ((l >> 5) << 3) + e;
            wc[p * 8 + e] = (_Float16)Wih[((long)(gate * 512 + j)) * 513 + k];
        }
    }
    // WN: p = (cix*16 + kt)*64 + l
    for (long p = i; p < 32768; p += stride) {
        int l = (int)(p & 63);
        long t = p >> 6;
        int kt = (int)(t & 15), cix = (int)(t >> 4);
        int j = cix * 16 + (l & 15);
        #pragma unroll
        for (int e = 0; e < 8; ++e) {
            int k = kt * 32 + ((l >> 4) << 3) + e;
            wn[p * 8 + e] = (_Float16)Wih[((long)(1024 + j)) * 513 + k];
        }
    }
    // ls: p = (nt*16 + kt)*64 + l
    for (long p = i; p < 32768; p += stride) {
        int l = (int)(p & 63);
        long t = p >> 6;
        int kt = (int)(t & 15), nt = (int)(t >> 4);
        int n = nt * 16 + (l & 15);
        #pragma unroll
        for (int e = 0; e < 8; ++e) {
            int k = kt * 32 + ((l >> 4) << 3) + e;
            wsls[p * 8 + e] = (_Float16)Ws[(long)k * 512 + n];
        }
    }
    for (long p = i; p < 278528; p += stride) ws[WS_D + p] = 0.0f;   // d+x (pads stay 0)
    if (i < 256) ((unsigned*)(ws + WS_BAR))[i] = 0u;
}

// ---------------- main persistent cooperative kernel ----------------
__global__ void __launch_bounds__(NTHREADS, 4) fused_kernel(
        const float* __restrict__ hiddens, const float* __restrict__ allys,
        const float* __restrict__ bs,
        const float* __restrict__ Wo, const float* __restrict__ bo,
        const float* __restrict__ bh,
        const float* __restrict__ b_ih, const float* __restrict__ b_hh,
        const float* __restrict__ Wih,
        const float* __restrict__ W1, const float* __restrict__ b1,
        const float* __restrict__ W2, const float* __restrict__ b2,
        const float* __restrict__ W3, const float* __restrict__ b3,
        const float* __restrict__ W4, const float* __restrict__ b4,
        float* __restrict__ ws, float* __restrict__ out) {
    const int tid = threadIdx.x;

    float* dw  = ws + WS_D;
    float* xw  = ws + WS_X;
    float* lhw = ws + WS_LH;
    const _Float16* waF = (const _Float16*)(ws + WS_WA);
    const _Float16* wcF = (const _Float16*)(ws + WS_WC);
    const _Float16* wnF = (const _Float16*)(ws + WS_WN);
    const _Float16* wsF = (const _Float16*)(ws + WS_WS);
    unsigned* barbase = (unsigned*)(ws + WS_BAR);

    extern __shared__ char smem[];
    char*           xhi   = smem + L_XHI;
    char*           xlo   = smem + L_XLO;
    unsigned short* lsb   = (unsigned short*)(smem + L_LSB);
    float*          ghs   = (float*)(smem + L_GH);
    float*          gis   = (float*)(smem + L_GI);
    float*          lh_s  = (float*)(smem + L_LH);
    float*          wo_s  = (float*)(smem + L_WO);
    float*          e_s   = (float*)(smem + L_E);
    float*          att_s = (float*)(smem + L_ATT);
    float*          cp_s  = (float*)(smem + L_CP);
    float*          h1p   = (float*)(smem + L_H1P);
    float*          h1s   = (float*)(smem + L_H1S);
    float*          h2p   = (float*)(smem + L_H2P);
    float*          h2s   = (float*)(smem + L_H2S);
    float*          h3p   = (float*)(smem + L_H3P);
    int*            misc  = (int*)(smem + L_MISC);
    float*          pbuf  = (float*)(smem + L_PB);

    // ---- dynamic XCD-local grouping (155KB LDS forces 1 block/CU -> 32/XCD) ----
    if (tid == 0) {
        unsigned xcc;
        asm volatile("s_getreg_b32 %0, hwreg(HW_REG_XCC_ID)" : "=s"(xcc));
        int gx = (int)(xcc & 7u);
        unsigned rk = __hip_atomic_fetch_add(barbase + gx * 32 + 1, 1u,
                                             __ATOMIC_RELAXED, __HIP_MEMORY_SCOPE_AGENT);
        misc[0] = gx;
        misc[1] = (int)(rk & 31u);
    }
    __syncthreads();
    const int g = misc[0], cix = misc[1];
    const int myb = g * 32 + cix;
    unsigned* bar = barbase + (g << 5);
    unsigned epoch = 0;

    const int sS = tid & 511, th = tid >> 9;
    const int rowE = tid >> 4, jE = tid & 15;          // gate-epilogue map (tid<512)
    const int jgE = cix * 16 + jE;
    const float* gPanelD = dw + (long)g * GSIZE * RSTRIDE;
    const float* gPanelX = xw + (long)g * GSIZE * RSTRIDE;

    // per-thread k=512 weight column (x-scalar fold)
    float w512r = 0.f, w512z = 0.f, w512n = 0.f;
    if (tid < 512) {
        w512r = Wih[(long)jgE * 513 + 512];
        w512z = Wih[(long)(512 + jgE) * 513 + 512];
        w512n = Wih[(long)(1024 + jgE) * 513 + 512];
    }

    float hreg[24];
    if (tid < NS) wo_s[tid] = Wo[tid];
    #pragma unroll
    for (int q = 0; q < 24; ++q)
        hreg[q] = hiddens[((long)myb * NT + th * 24 + q) * NS + sS];

    // ==== startup: zero panels, then ls = hiddens@Ws + bs via f16 MFMA ====
    for (int i = tid; i < 4352; i += NTHREADS) *(f4v*)(smem + i * 16) = (f4v){0,0,0,0};
    for (int ch = 0; ch < 2; ++ch) {
        __syncthreads();
        {
            const float* src = hiddens + ((long)myb * NT + ch * 24) * NS;
            const int i0 = tid * 12;
            #pragma unroll
            for (int j3 = 0; j3 < 3; ++j3) {
                int idx = i0 + j3 * 4;
                f4v v = *(const f4v*)(src + idx);
                int row = idx >> 9, col = idx & 511;
                h4v h, l;
                #pragma unroll
                for (int e = 0; e < 4; ++e) { _Float16 hh, ll; split16_(v[e], hh, ll); h[e] = hh; l[e] = ll; }
                *(h4v*)(xhi + row * XROWB + col * 2) = h;
                *(h4v*)(xlo + row * XROWB + col * 2) = l;
            }
        }
        __syncthreads();
        lsGemm(smem, wsF, tid, ch, lsb, bs);
    }
    __syncthreads();

    const float bo0 = bo[0];

    // ================= time scan: 3 group barriers per step =================
    for (int t = 0; t < NT; ++t) {
        // ---- A: stage d -> panels; MFMA gh + lh (K-split) ----
        stagePanel(gPanelD, xhi, xlo, tid);
        __syncthreads();
        gemmA(smem, waF, cix, g, tid, ghs, lhw, pbuf, bh, b_hh, true);
        gbar(bar, &epoch);

        // ---- B: attention for own row ----
        if (tid < 128) {
            f4v v = cload4(lhw + (long)myb * NS + tid * 4);
            cwait();
            *(f4v*)(lh_s + tid * 4) = v;
        }
        if (tid == 0) cstore1(xw + (long)myb * RSTRIDE + XSLOT, allys[myb * NT + t]);
        __syncthreads();
        {
            const int wv = tid >> 6, ln = tid & 63;
            for (int q = 0; q < 3; ++q) {
                const int tt = wv * 3 + q;
                float p = 0.f;
                #pragma unroll
                for (int i2 = 0; i2 < 8; ++i2) {
                    int s = ln + (i2 << 6);
                    p = fmaf(wo_s[s], ftanh_(lh_s[s] + bf2f_(lsb[tt * NS + s])), p);
                }
                #pragma unroll
                for (int off = 32; off >= 1; off >>= 1) p += __shfl_xor(p, off, 64);
                if (ln == 0) e_s[tt] = p + bo0;
            }
        }
        __syncthreads();
        if (tid < 64) {
            float v = (tid < NT) ? e_s[tid] : -1e30f;
            float m = v;
            #pragma unroll
            for (int off = 32; off >= 1; off >>= 1) m = fmaxf(m, __shfl_xor(m, off, 64));
            float ex = (tid < NT) ? __expf(v - m) : 0.0f;
            float ssum = ex;
            #pragma unroll
            for (int off = 32; off >= 1; off >>= 1) ssum += __shfl_xor(ssum, off, 64);
            if (tid < NT) att_s[tid] = ex * frcp_(ssum);
        }
        __syncthreads();
        {
            float p = 0.f;
            #pragma unroll
            for (int q = 0; q < 24; ++q) p = fmaf(att_s[th * 24 + q], hreg[q], p);
            if (th == 0) cp_s[sS] = p;
            __syncthreads();
            if (th == 1) cstore1(xw + (long)myb * RSTRIDE + sS, p + cp_s[sS]);
        }
        gbar(bar, &epoch);

        // ---- C: stage x -> panels; MFMA gi (K-split); GRU gates ----
        float hp = 0.f;
        if (tid < 512) hp = cload1(dw + (long)(g * 32 + rowE) * RSTRIDE + jgE);
        stagePanel(gPanelX, xhi, xlo, tid);
        __syncthreads();
        gemmC(smem, wcF, wnF, cix, tid, gis, pbuf, b_ih);
        __syncthreads();
        if (tid < 512) {
            float x512f = (float)*(const _Float16*)(xhi + rowE * XROWB + 1024)
                        + (float)*(const _Float16*)(xlo + rowE * XROWB + 1024);
            float gr  = gis[rowE * 17 + jE]       + ghs[rowE * 17 + jE]       + x512f * w512r;
            float gz  = gis[544 + rowE * 17 + jE] + ghs[544 + rowE * 17 + jE] + x512f * w512z;
            float gni = gis[1088 + rowE * 17 + jE] + x512f * w512n;
            float gnh = ghs[1088 + rowE * 17 + jE];
            float rg = fsig_(gr);
            float zg = fsig_(gz);
            float ng = ftanh_(gni + rg * gnh);
            cstore1(dw + (long)(g * 32 + rowE) * RSTRIDE + jgE, (1.f - zg) * ng + zg * hp);
        }
        gbar(bar, &epoch);
    }

    // ================= k_wk_ahead head =================
    for (int kk = 0; kk < KAHEAD; ++kk) {
        {
            float v = 0.f;
            if (tid < NS) v = cload1(dw + (long)myb * RSTRIDE + tid);
            cwait();
            if (tid < NS) lh_s[tid] = v;
        }
        __syncthreads();
        {   // M1: 512 -> 256
            int n = tid & 255, q4 = tid >> 8;
            const float* av = lh_s + q4 * 128;
            const float* wp = W1 + (long)(q4 * 128) * 256 + n;
            float acc = 0.f;
            #pragma unroll 4
            for (int k2 = 0; k2 < 128; ++k2) { acc = fmaf(av[k2], wp[0], acc); wp += 256; }
            h1p[n * 4 + q4] = acc;
        }
        __syncthreads();
        if (tid < 256) {
            float v = h1p[tid * 4] + h1p[tid * 4 + 1] + h1p[tid * 4 + 2] + h1p[tid * 4 + 3];
            h1s[tid] = lrelu_(v + b1[tid]);
        }
        __syncthreads();
        if (tid < 512) {   // M2: 256 -> 128
            int n = tid & 127, q4 = tid >> 7;
            const float* av = h1s + q4 * 64;
            const float* wp = W2 + (long)(q4 * 64) * 128 + n;
            float acc = 0.f;
            #pragma unroll 4
            for (int k2 = 0; k2 < 64; ++k2) { acc = fmaf(av[k2], wp[0], acc); wp += 128; }
            h2p[n * 4 + q4] = acc;
        }
        __syncthreads();
        if (tid < 128) {
            float v = h2p[tid * 4] + h2p[tid * 4 + 1] + h2p[tid * 4 + 2] + h2p[tid * 4 + 3];
            h2s[tid] = lrelu_(v + b2[tid]);
        }
        __syncthreads();
        if (tid < 256) {   // M3: 128 -> 64
            int n = tid & 63, q4 = tid >> 6;
            const float* av = h2s + q4 * 32;
            const float* wp = W3 + (long)(q4 * 32) * 64 + n;
            float acc = 0.f;
            #pragma unroll 4
            for (int k2 = 0; k2 < 32; ++k2) { acc = fmaf(av[k2], wp[0], acc); wp += 64; }
            h3p[n * 4 + q4] = acc;
        }
        __syncthreads();
        if (tid < 64) {    // M3 epilogue + M4
            float v = h3p[tid * 4] + h3p[tid * 4 + 1] + h3p[tid * 4 + 2] + h3p[tid * 4 + 3];
            float h3v = lrelu_(v + b3[tid]);
            float p = h3v * W4[tid];
            #pragma unroll
            for (int off = 32; off >= 1; off >>= 1) p += __shfl_xor(p, off, 64);
            if (tid == 0) {
                float o = lrelu_(p + b4[0]);
                out[myb * KAHEAD + kk] = o;
                cstore1(xw + (long)myb * RSTRIDE + XSLOT, o);
            }
        }
        if (kk < KAHEAD - 1) {
            gbar(bar, &epoch);
            float hp = 0.f;
            if (tid < 512) hp = cload1(dw + (long)(g * 32 + rowE) * RSTRIDE + jgE);
            stagePanel(gPanelD, xhi, xlo, tid);
            __syncthreads();
            gemmA(smem, waF, cix, g, tid, ghs, lhw, pbuf, bh, b_hh, false);
            __syncthreads();
            stagePanel(gPanelX, xhi, xlo, tid);
            __syncthreads();
            gemmC(smem, wcF, wnF, cix, tid, gis, pbuf, b_ih);
            __syncthreads();
            if (tid < 512) {
                float x512f = (float)*(const _Float16*)(xhi + rowE * XROWB + 1024)
                            + (float)*(const _Float16*)(xlo + rowE * XROWB + 1024);
                float gr  = gis[rowE * 17 + jE]       + ghs[rowE * 17 + jE]       + x512f * w512r;
                float gz  = gis[544 + rowE * 17 + jE] + ghs[544 + rowE * 17 + jE] + x512f * w512z;
                float gni = gis[1088 + rowE * 17 + jE] + x512f * w512n;
                float gnh = ghs[1088 + rowE * 17 + jE];
                float rg = fsig_(gr);
                float zg = fsig_(gz);
                float ng = ftanh_(gni + rg * gnh);
                cstore1(dw + (long)(g * 32 + rowE) * RSTRIDE + jgE, (1.f - zg) * ng + zg * hp);
            }
            gbar(bar, &epoch);
        }
    }
}

// ---------------- host ----------------
extern "C" void kernel_launch(void* const* d_in, const int* in_sizes, int n_in,
                              void* d_out, int out_size, void* d_ws, size_t ws_size,
                              hipStream_t stream) {
    const float* hiddens = (const float*)d_in[0];
    const float* allys   = (const float*)d_in[1];
    const float* Wh   = (const float*)d_in[3];
    const float* bh   = (const float*)d_in[4];
    const float* Ws   = (const float*)d_in[5];
    const float* bs   = (const float*)d_in[6];
    const float* Wo   = (const float*)d_in[7];
    const float* bo   = (const float*)d_in[8];
    const float* W_ih = (const float*)d_in[9];
    const float* W_hh = (const float*)d_in[10];
    const float* b_ih = (const float*)d_in[11];
    const float* b_hh = (const float*)d_in[12];
    const float* W1 = (const float*)d_in[13];
    const float* b1 = (const float*)d_in[14];
    const float* W2 = (const float*)d_in[15];
    const float* b2 = (const float*)d_in[16];
    const float* W3 = (const float*)d_in[17];
    const float* b3 = (const float*)d_in[18];
    const float* W4 = (const float*)d_in[19];
    const float* b4 = (const float*)d_in[20];
    float* wsf = (float*)d_ws;
    float* outf = (float*)d_out;

    if (ws_size < (size_t)WS_FLOATS * sizeof(float)) {
        fprintf(stderr, "kernel_launch: workspace too small (%zu < %zu)\n",
                ws_size, (size_t)WS_FLOATS * sizeof(float));
        return;
    }

    prep_kernel<<<dim3(2048), dim3(256), 0, stream>>>(W_hh, W_ih, Wh, Ws, wsf);

    (void)hipFuncSetAttribute((const void*)fused_kernel,
                              hipFuncAttributeMaxDynamicSharedMemorySize, LDS_BYTES);

    void* args[] = { &hiddens, &allys, &bs, &Wo, &bo, &bh,
                     &b_ih, &b_hh, &W_ih, &W1, &b1, &W2, &b2, &W3, &b3, &W4, &b4,
                     &wsf, &outf };
    hipError_t e = hipLaunchCooperativeKernel((void*)fused_kernel,
                                              dim3(NBLOCKS), dim3(NTHREADS),
                                              args, LDS_BYTES, stream);
    if (e != hipSuccess) {
        fprintf(stderr, "coop launch failed (%d); plain fallback\n", (int)e);
        (void)hipGetLastError();
        fused_kernel<<<dim3(NBLOCKS), dim3(NTHREADS), LDS_BYTES, stream>>>(
            hiddens, allys, bs, Wo, bo, bh, b_ih, b_hh, W_ih,
            W1, b1, W2, b2, W3, b3, W4, b4, wsf, outf);
    }
}

// Round 8
// 1812.264 us; speedup vs baseline: 2.5609x; 1.1133x over previous
//
#include <hip/hip_runtime.h>
#include <cstdio>

#ifndef __has_builtin
#define __has_builtin(x) 0
#endif

// ---------------- problem constants ----------------
#define NB      256
#define NT      48
#define NS      512
#define KAHEAD  4
#define NTHREADS 1024
#define NBLOCKS  256
#define GSIZE    32
#define RSTRIDE  544     // exchange row floats (512 d / 513 x used)
#define XSLOT    512     // x scalar slot
#define XROWB    1088    // LDS f16 panel row stride bytes

// ---------------- workspace (float offsets) ----------------
#define WS_D     0              // [256][544] d exchange fp32
#define WS_X     139264         // [256][544] x exchange
#define WS_LH    278528         // [256][512] lh exchange
#define WS_BAR   409600         // 256 uints
#define WS_WA    409856         // f16 [32 cix][2 nt][32 kt][512]
#define WS_WC    934144         // f16 [32 cix][32 kt][512]
#define WS_WN    1196288        // f16 [32 cix][16 kt][512]
#define WS_WS    1327360        // f16 [32 nt][16 kt][512]
#define WS_FLOATS 1458432       // 5.83 MB

// ---------------- LDS (byte offsets), total 155408 ----------------
#define L_XHI    0              // f16 panel hi [32][1088B] 34816
#define L_XLO    34816
#define L_LSB    69632          // ushort [48][512] bf16 ls 49152
#define L_GH     118784         // float [3][32][17]
#define L_GI     125312
#define L_LH     131840
#define L_WO     133888
#define L_E      135936
#define L_ATT    136192
#define L_CP     136448
#define L_H1P    138496
#define L_H1S    142592
#define L_H2P    143616
#define L_H2S    145664
#define L_H3P    146176
#define L_MISC   147200
#define L_PB     147216         // float[2048] K-split partial buffer (8KB)
#define LDS_BYTES 155408

typedef float    f4v  __attribute__((ext_vector_type(4)));
typedef float    f16v __attribute__((ext_vector_type(16)));
typedef _Float16 h4v  __attribute__((ext_vector_type(4)));
typedef _Float16 h8v  __attribute__((ext_vector_type(8)));

// ---------------- MFMA (f16) ----------------
__device__ __forceinline__ f16v MFMA32(h8v a, h8v b, f16v c) {
    return __builtin_amdgcn_mfma_f32_32x32x16_f16(a, b, c, 0, 0, 0);
}
__device__ __forceinline__ f4v MFMA16(h8v a, h8v b, f4v c) {
    return __builtin_amdgcn_mfma_f32_16x16x32_f16(a, b, c, 0, 0, 0);
}

// bit-reinterpret between f4v (4 fp32) and h8v (8 f16) register storage
#if __has_builtin(__builtin_bit_cast)
#define F2H_BITS(v) __builtin_bit_cast(h8v, (v))
#define H2F_BITS(v) __builtin_bit_cast(f4v, (v))
#else
__device__ __forceinline__ h8v f2h_bits_(f4v v) { union { f4v f; h8v h; } u; u.f = v; return u.h; }
__device__ __forceinline__ f4v h2f_bits_(h8v v) { union { f4v f; h8v h; } u; u.h = v; return u.f; }
#define F2H_BITS(v) f2h_bits_(v)
#define H2F_BITS(v) h2f_bits_(v)
#endif

// ---------------- math ----------------
__device__ __forceinline__ float frcp_(float x) {
#if __has_builtin(__builtin_amdgcn_rcpf)
    return __builtin_amdgcn_rcpf(x);
#else
    return 1.0f / x;
#endif
}
__device__ __forceinline__ float ftanh_(float x) {
    float e = __expf(2.0f * x);
    return 1.0f - 2.0f * frcp_(e + 1.0f);
}
__device__ __forceinline__ float fsig_(float x) { return frcp_(1.0f + __expf(-x)); }
__device__ __forceinline__ float lrelu_(float x) { return fmaxf(x, 0.01f * x); }
__device__ __forceinline__ unsigned short rne16_(unsigned u) {
    return (unsigned short)((u + 0x7FFFu + ((u >> 16) & 1u)) >> 16);
}
__device__ __forceinline__ float bf2f_(unsigned short b) {
    return __uint_as_float(((unsigned)b) << 16);
}
__device__ __forceinline__ void split16_(float v, _Float16& hi, _Float16& lo) {
    _Float16 h = (_Float16)v;
    hi = h;
    lo = (_Float16)(v - (float)h);
}

// ---------------- XCD-local (L2-scope) coherent access: sc0; nt = evict-first ----------------
__device__ __forceinline__ void cstore1(float* p, float v) {
    asm volatile("global_store_dword %0, %1, off sc0 nt" :: "v"(p), "v"(v) : "memory");
}
__device__ __forceinline__ f4v cload4(const float* p) {
    f4v v;
    asm volatile("global_load_dwordx4 %0, %1, off sc0" : "=v"(v) : "v"(p));
    return v;
}
__device__ __forceinline__ float cload1(const float* p) {
    float v;
    asm volatile("global_load_dword %0, %1, off sc0" : "=v"(v) : "v"(p));
    return v;
}
__device__ __forceinline__ void cwait() {
    asm volatile("s_waitcnt vmcnt(0)" ::: "memory");
    __builtin_amdgcn_sched_barrier(0);
}

// Group barrier (agent-scope counter; r2-r7 proven).
__device__ __forceinline__ void gbar(unsigned* bar, unsigned* epoch) {
    asm volatile("s_waitcnt vmcnt(0)" ::: "memory");
    __syncthreads();
    if (threadIdx.x == 0) {
        *epoch += GSIZE;
        __hip_atomic_fetch_add(bar, 1u, __ATOMIC_RELAXED, __HIP_MEMORY_SCOPE_AGENT);
        unsigned target = *epoch;
        int guard = 0;
        while (__hip_atomic_load(bar, __ATOMIC_RELAXED, __HIP_MEMORY_SCOPE_AGENT) < target) {
#if __has_builtin(__builtin_amdgcn_s_sleep)
            __builtin_amdgcn_s_sleep(2);
#endif
            if (++guard > (1 << 16)) break;
        }
    }
    __syncthreads();
}

// ---------------- staging: fp32 exchange panel -> LDS f16 hi/lo ----------------
__device__ __forceinline__ void cvtStore_(char* hiB, char* loB, int idx, f4v v) {
    unsigned row = (unsigned)idx / 544u;
    unsigned col = (unsigned)idx - row * 544u;
    h4v h, l;
    #pragma unroll
    for (int i = 0; i < 4; ++i) { _Float16 hh, ll; split16_(v[i], hh, ll); h[i] = hh; l[i] = ll; }
    *(h4v*)(hiB + row * XROWB + col * 2) = h;
    *(h4v*)(loB + row * XROWB + col * 2) = l;
}
__device__ __forceinline__ void stagePanel(const float* __restrict__ gsrc,
                                           char* __restrict__ hiB,
                                           char* __restrict__ loB, int tid) {
    f4v v0 = cload4(gsrc + tid * 4);
    f4v v1 = cload4(gsrc + 4096 + tid * 4);
    f4v v2 = cload4(gsrc + 8192 + tid * 4);
    f4v v3 = cload4(gsrc + 12288 + tid * 4);
    f4v v4 = {0.f, 0.f, 0.f, 0.f};
    if (tid < 256) v4 = cload4(gsrc + 16384 + tid * 4);
    cwait();
    cvtStore_(hiB, loB, tid * 4, v0);
    cvtStore_(hiB, loB, 4096 + tid * 4, v1);
    cvtStore_(hiB, loB, 8192 + tid * 4, v2);
    cvtStore_(hiB, loB, 12288 + tid * 4, v3);
    if (tid < 256) cvtStore_(hiB, loB, 16384 + tid * 4, v4);
}

// ---------------- GEMMs with register-resident B (macros: guaranteed inline) ----------------
// waves 0-3: gemmA (nt2=w&1, kc=w>>1); internal __syncthreads reached by ALL threads
#define DO_GEMMA(doLH) do {                                                          \
    f16v acc_ = (f16v){0,0,0,0,0,0,0,0,0,0,0,0,0,0,0,0};                             \
    if (w < 4) {                                                                     \
        const int kc_ = w >> 1;                                                      \
        const int aoff_ = (l & 31) * XROWB + ((l >> 5) << 4);                        \
        _Pragma("unroll")                                                            \
        for (int kt = 0; kt < 16; ++kt) {                                            \
            h8v ah = *(const h8v*)(smem + L_XHI + aoff_ + (kc_ * 16 + kt) * 32);     \
            h8v al = *(const h8v*)(smem + L_XLO + aoff_ + (kc_ * 16 + kt) * 32);     \
            acc_ = MFMA32(ah, wreg[kt], acc_);                                       \
            acc_ = MFMA32(al, wreg[kt], acc_);                                       \
        }                                                                            \
        if (kc_ == 1) {                                                              \
            _Pragma("unroll")                                                        \
            for (int r = 0; r < 16; ++r) pbuf[(w & 1) * 1024 + r * 64 + l] = acc_[r];\
        }                                                                            \
    }                                                                                \
    __syncthreads();                                                                 \
    if (w < 2) {                                                                     \
        _Pragma("unroll")                                                            \
        for (int r = 0; r < 16; ++r) acc_[r] += pbuf[w * 1024 + r * 64 + l];         \
        const int c_ = w * 32 + (l & 31);                                            \
        const int rb_ = (l >> 5) << 2;                                               \
        if (c_ < 16) {                                                               \
            if (doLH) {                                                              \
                const int j_ = cix * 16 + c_;                                        \
                const float bb_ = bh[j_];                                            \
                _Pragma("unroll")                                                    \
                for (int r = 0; r < 16; ++r) {                                       \
                    int row_ = (r & 3) + ((r >> 2) << 3) + rb_;                      \
                    cstore1(lhw + (long)(g * 32 + row_) * NS + j_, acc_[r] + bb_);   \
                }                                                                    \
            }                                                                        \
        } else {                                                                     \
            const int gate_ = (c_ - 16) >> 4, jj_ = (c_ - 16) & 15;                  \
            const float bb_ = b_hh[gate_ * 512 + cix * 16 + jj_];                    \
            _Pragma("unroll")                                                        \
            for (int r = 0; r < 16; ++r) {                                           \
                int row_ = (r & 3) + ((r >> 2) << 3) + rb_;                          \
                ghs[gate_ * 544 + row_ * 17 + jj_] = acc_[r] + bb_;                  \
            }                                                                        \
        }                                                                            \
    }                                                                                \
} while (0)

// waves 4-5: rz (kc=w-4); waves 6-7: n (kc=w-6); internal __syncthreads for all
#define DO_GEMMC() do {                                                              \
    f16v acc_ = (f16v){0,0,0,0,0,0,0,0,0,0,0,0,0,0,0,0};                             \
    f4v an0_ = {0.f,0.f,0.f,0.f}, an1_ = {0.f,0.f,0.f,0.f};                          \
    if (w == 4 || w == 5) {                                                          \
        const int kc_ = w - 4;                                                       \
        const int aoff_ = (l & 31) * XROWB + ((l >> 5) << 4);                        \
        _Pragma("unroll")                                                            \
        for (int kt = 0; kt < 16; ++kt) {                                            \
            h8v ah = *(const h8v*)(smem + L_XHI + aoff_ + (kc_ * 16 + kt) * 32);     \
            h8v al = *(const h8v*)(smem + L_XLO + aoff_ + (kc_ * 16 + kt) * 32);     \
            acc_ = MFMA32(ah, wreg[kt], acc_);                                       \
            acc_ = MFMA32(al, wreg[kt], acc_);                                       \
        }                                                                            \
        if (kc_ == 1) {                                                              \
            _Pragma("unroll")                                                        \
            for (int r = 0; r < 16; ++r) pbuf[r * 64 + l] = acc_[r];                 \
        }                                                                            \
    } else if (w == 6 || w == 7) {                                                   \
        const int kc_ = w - 6;                                                       \
        const int a0_ = (l & 15) * XROWB + ((l >> 4) << 4);                          \
        const int a1_ = a0_ + 16 * XROWB;                                            \
        _Pragma("unroll")                                                            \
        for (int kt = 0; kt < 8; ++kt) {                                             \
            const int kb_ = (kc_ * 8 + kt) * 64;                                     \
            h8v ah0 = *(const h8v*)(smem + L_XHI + a0_ + kb_);                       \
            h8v al0 = *(const h8v*)(smem + L_XLO + a0_ + kb_);                       \
            h8v ah1 = *(const h8v*)(smem + L_XHI + a1_ + kb_);                       \
            h8v al1 = *(const h8v*)(smem + L_XLO + a1_ + kb_);                       \
            an0_ = MFMA16(ah0, wreg[kt], an0_); an0_ = MFMA16(al0, wreg[kt], an0_);  \
            an1_ = MFMA16(ah1, wreg[kt], an1_); an1_ = MFMA16(al1, wreg[kt], an1_);  \
        }                                                                            \
        if (kc_ == 1) {                                                              \
            _Pragma("unroll")                                                        \
            for (int r = 0; r < 4; ++r) {                                            \
                pbuf[1024 + r * 64 + l] = an0_[r];                                   \
                pbuf[1280 + r * 64 + l] = an1_[r];                                   \
            }                                                                        \
        }                                                                            \
    }                                                                                \
    __syncthreads();                                                                 \
    if (w == 4) {                                                                    \
        _Pragma("unroll")                                                            \
        for (int r = 0; r < 16; ++r) acc_[r] += pbuf[r * 64 + l];                    \
        const int c_ = l & 31, gate_ = c_ >> 4, jj_ = c_ & 15;                       \
        const int rb_ = (l >> 5) << 2;                                               \
        const float bb_ = b_ih[gate_ * 512 + cix * 16 + jj_];                        \
        _Pragma("unroll")                                                            \
        for (int r = 0; r < 16; ++r) {                                               \
            int row_ = (r & 3) + ((r >> 2) << 3) + rb_;                              \
            gis[gate_ * 544 + row_ * 17 + jj_] = acc_[r] + bb_;                      \
        }                                                                            \
    } else if (w == 6) {                                                             \
        const int jj_ = l & 15;                                                      \
        const float bb_ = b_ih[1024 + cix * 16 + jj_];                               \
        _Pragma("unroll")                                                            \
        for (int r = 0; r < 4; ++r) {                                                \
            int row_ = ((l >> 4) << 2) + r;                                          \
            gis[1088 + row_ * 17 + jj_] = an0_[r] + pbuf[1024 + r * 64 + l] + bb_;   \
            gis[1088 + (16 + row_) * 17 + jj_] = an1_[r] + pbuf[1280 + r * 64 + l] + bb_; \
        }                                                                            \
    }                                                                                \
} while (0)

// startup ls GEMM: 16 waves, 16x16x32_f16, K=512 (B streamed once)
__device__ __forceinline__ void lsGemm(const char* smem, const _Float16* WS_,
        int tid, int ch, unsigned short* lsb, const float* bs) {
    const int w = tid >> 6, l = tid & 63;
    const int mt = w & 1, ng = w >> 1;
    const int aoff = (mt * 16 + (l & 15)) * XROWB + ((l >> 4) << 4);
    f4v acc[4] = {{0,0,0,0},{0,0,0,0},{0,0,0,0},{0,0,0,0}};
    for (int kt = 0; kt < 16; ++kt) {
        h8v ah = *(const h8v*)(smem + L_XHI + aoff + kt * 64);
        h8v al = *(const h8v*)(smem + L_XLO + aoff + kt * 64);
        #pragma unroll
        for (int i = 0; i < 4; ++i) {
            const _Float16* bp = WS_ + ((long)((ng * 4 + i) * 16 + kt)) * 512 + (l << 3);
            h8v bb = *(const h8v*)bp;
            acc[i] = MFMA16(ah, bb, acc[i]);
            acc[i] = MFMA16(al, bb, acc[i]);
        }
    }
    #pragma unroll
    for (int i = 0; i < 4; ++i) {
        const int n = (ng * 4 + i) * 16 + (l & 15);
        const float bsv = bs[n];
        #pragma unroll
        for (int r = 0; r < 4; ++r) {
            int row = mt * 16 + ((l >> 4) << 2) + r;
            if (row < 24)
                lsb[(ch * 24 + row) * NS + n] = rne16_(__float_as_uint(acc[i][r] + bsv));
        }
    }
}

// ---------------- prep: f16 fragment packing + zeroing (unchanged r7) ----------------
__global__ void prep_kernel(const float* __restrict__ Whh,
                            const float* __restrict__ Wih,
                            const float* __restrict__ Wh,
                            const float* __restrict__ Ws,
                            float* __restrict__ ws) {
    long i = (long)blockIdx.x * blockDim.x + threadIdx.x;
    long stride = (long)gridDim.x * blockDim.x;
    _Float16* wa = (_Float16*)(ws + WS_WA);
    _Float16* wc = (_Float16*)(ws + WS_WC);
    _Float16* wn = (_Float16*)(ws + WS_WN);
    _Float16* wsls = (_Float16*)(ws + WS_WS);

    for (long p = i; p < 131072; p += stride) {
        int l = (int)(p & 63);
        long t = p >> 6;
        int kt = (int)(t & 31);
        int u = (int)(t >> 5);
        int nt = u & 1, cix = u >> 1;
        int c = nt * 32 + (l & 31);
        #pragma unroll
        for (int e = 0; e < 8; ++e) {
            int k = kt * 16 + ((l >> 5) << 3) + e;
            float wv;
            if (c < 16) wv = Wh[(long)k * 512 + cix * 16 + c];
            else {
                int gate = (c - 16) >> 4, j = cix * 16 + ((c - 16) & 15);
                wv = Whh[((long)(gate * 512 + j)) * 512 + k];
            }
            wa[p * 8 + e] = (_Float16)wv;
        }
    }
    for (long p = i; p < 65536; p += stride) {
        int l = (int)(p & 63);
        long t = p >> 6;
        int kt = (int)(t & 31), cix = (int)(t >> 5);
        int c = l & 31, gate = c >> 4, j = cix * 16 + (c & 15);
        #pragma unroll
        for (int e = 0; e < 8; ++e) {
            int k = kt * 16 + ((l >> 5) << 3) + e;
            wc[p * 8 + e] = (_Float16)Wih[((long)(gate * 512 + j)) * 513 + k];
        }
    }
    for (long p = i; p < 32768; p += stride) {
        int l = (int)(p & 63);
        long t = p >> 6;
        int kt = (int)(t & 15), cix = (int)(t >> 4);
        int j = cix * 16 + (l & 15);
        #pragma unroll
        for (int e = 0; e < 8; ++e) {
            int k = kt * 32 + ((l >> 4) << 3) + e;
            wn[p * 8 + e] = (_Float16)Wih[((long)(1024 + j)) * 513 + k];
        }
    }
    for (long p = i; p < 32768; p += stride) {
        int l = (int)(p & 63);
        long t = p >> 6;
        int kt = (int)(t & 15), nt = (int)(t >> 4);
        int n = nt * 16 + (l & 15);
        #pragma unroll
        for (int e = 0; e < 8; ++e) {
            int k = kt * 32 + ((l >> 4) << 3) + e;
            wsls[p * 8 + e] = (_Float16)Ws[(long)k * 512 + n];
        }
    }
    for (long p = i; p < 278528; p += stride) ws[WS_D + p] = 0.0f;
    if (i < 256) ((unsigned*)(ws + WS_BAR))[i] = 0u;
}

// ---------------- main persistent cooperative kernel ----------------
__global__ void __launch_bounds__(NTHREADS, 4) fused_kernel(
        const float* __restrict__ hiddens, const float* __restrict__ allys,
        const float* __restrict__ bs,
        const float* __restrict__ Wo, const float* __restrict__ bo,
        const float* __restrict__ bh,
        const float* __restrict__ b_ih, const float* __restrict__ b_hh,
        const float* __restrict__ Wih,
        const float* __restrict__ W1, const float* __restrict__ b1,
        const float* __restrict__ W2, const float* __restrict__ b2,
        const float* __restrict__ W3, const float* __restrict__ b3,
        const float* __restrict__ W4, const float* __restrict__ b4,
        float* __restrict__ ws, float* __restrict__ out) {
    const int tid = threadIdx.x;

    float* dw  = ws + WS_D;
    float* xw  = ws + WS_X;
    float* lhw = ws + WS_LH;
    const _Float16* waF = (const _Float16*)(ws + WS_WA);
    const _Float16* wcF = (const _Float16*)(ws + WS_WC);
    const _Float16* wnF = (const _Float16*)(ws + WS_WN);
    const _Float16* wsF = (const _Float16*)(ws + WS_WS);
    unsigned* barbase = (unsigned*)(ws + WS_BAR);

    extern __shared__ char smem[];
    char*           xhi   = smem + L_XHI;
    char*           xlo   = smem + L_XLO;
    unsigned short* lsb   = (unsigned short*)(smem + L_LSB);
    float*          ghs   = (float*)(smem + L_GH);
    float*          gis   = (float*)(smem + L_GI);
    float*          lh_s  = (float*)(smem + L_LH);
    float*          wo_s  = (float*)(smem + L_WO);
    float*          e_s   = (float*)(smem + L_E);
    float*          att_s = (float*)(smem + L_ATT);
    float*          h1p   = (float*)(smem + L_H1P);
    float*          h1s   = (float*)(smem + L_H1S);
    float*          h2p   = (float*)(smem + L_H2P);
    float*          h2s   = (float*)(smem + L_H2S);
    float*          h3p   = (float*)(smem + L_H3P);
    int*            misc  = (int*)(smem + L_MISC);
    float*          pbuf  = (float*)(smem + L_PB);

    // ---- dynamic XCD-local grouping (155KB LDS forces 1 block/CU -> 32/XCD) ----
    if (tid == 0) {
        unsigned xcc;
        asm volatile("s_getreg_b32 %0, hwreg(HW_REG_XCC_ID)" : "=s"(xcc));
        int gx = (int)(xcc & 7u);
        unsigned rk = __hip_atomic_fetch_add(barbase + gx * 32 + 1, 1u,
                                             __ATOMIC_RELAXED, __HIP_MEMORY_SCOPE_AGENT);
        misc[0] = gx;
        misc[1] = (int)(rk & 31u);
    }
    __syncthreads();
    const int g = misc[0], cix = misc[1];
    const int myb = g * 32 + cix;
    unsigned* bar = barbase + (g << 5);
    unsigned epoch = 0;

    const int w = tid >> 6, l = tid & 63;
    const int sS = tid & 511, th = tid >> 9;
    const int rowE = tid >> 4, jE = tid & 15;          // gate-epilogue map (tid<512)
    const int jgE = cix * 16 + jE;
    const float* gPanelD = dw + (long)g * GSIZE * RSTRIDE;
    const float* gPanelX = xw + (long)g * GSIZE * RSTRIDE;

    // per-thread k=512 weight column (x-scalar fold)
    float w512r = 0.f, w512z = 0.f, w512n = 0.f;
    if (tid < 512) {
        w512r = Wih[(long)jgE * 513 + 512];
        w512z = Wih[(long)(512 + jgE) * 513 + 512];
        w512n = Wih[(long)(1024 + jgE) * 513 + 512];
    }

    if (tid < NS) wo_s[tid] = Wo[tid];

    // ==== startup: zero panels, then ls = hiddens@Ws + bs via f16 MFMA ====
    for (int i = tid; i < 4352; i += NTHREADS) *(f4v*)(smem + i * 16) = (f4v){0,0,0,0};
    for (int ch = 0; ch < 2; ++ch) {
        __syncthreads();
        {
            const float* src = hiddens + ((long)myb * NT + ch * 24) * NS;
            const int i0 = tid * 12;
            #pragma unroll
            for (int j3 = 0; j3 < 3; ++j3) {
                int idx = i0 + j3 * 4;
                f4v v = *(const f4v*)(src + idx);
                int row = idx >> 9, col = idx & 511;
                h4v h, lo;
                #pragma unroll
                for (int e = 0; e < 4; ++e) { _Float16 hh, ll; split16_(v[e], hh, ll); h[e] = hh; lo[e] = ll; }
                *(h4v*)(xhi + row * XROWB + col * 2) = h;
                *(h4v*)(xlo + row * XROWB + col * 2) = lo;
            }
        }
        __syncthreads();
        lsGemm(smem, wsF, tid, ch, lsb, bs);
    }
    __syncthreads();

    // ==== one-time register-resident data (weights / hiddens rows) ====
    // waves 0-3: WA (gemmA B-frags); 4-5: WC rz; 6-7: WN n; 8-15: hiddens[myb][*][s]
    h8v wreg[16];
    if (w < 4) {
        const _Float16* p = waF + ((long)((cix * 2 + (w & 1)) * 32 + (w >> 1) * 16)) * 512 + (l << 3);
        #pragma unroll
        for (int kt = 0; kt < 16; ++kt) wreg[kt] = *(const h8v*)(p + kt * 512);
    } else if (w < 6) {
        const _Float16* p = wcF + ((long)(cix * 32 + (w - 4) * 16)) * 512 + (l << 3);
        #pragma unroll
        for (int kt = 0; kt < 16; ++kt) wreg[kt] = *(const h8v*)(p + kt * 512);
    } else if (w < 8) {
        const _Float16* p = wnF + ((long)(cix * 16 + (w - 6) * 8)) * 512 + (l << 3);
        #pragma unroll
        for (int kt = 0; kt < 8; ++kt) wreg[kt] = *(const h8v*)(p + kt * 512);
    } else {
        const float* hb = hiddens + (long)myb * NT * NS + sS;
        #pragma unroll
        for (int q = 0; q < 12; ++q) {
            f4v v = { hb[(q * 4 + 0) * 512], hb[(q * 4 + 1) * 512],
                      hb[(q * 4 + 2) * 512], hb[(q * 4 + 3) * 512] };
            wreg[q] = F2H_BITS(v);
        }
    }

    const float bo0 = bo[0];

    // ================= time scan: 3 group barriers per step =================
    for (int t = 0; t < NT; ++t) {
        // ---- A: stage d -> panels; MFMA gh + lh (register weights) ----
        stagePanel(gPanelD, xhi, xlo, tid);
        __syncthreads();
        DO_GEMMA(true);
        gbar(bar, &epoch);

        // ---- B: attention for own row ----
        if (tid < 128) {
            f4v v = cload4(lhw + (long)myb * NS + tid * 4);
            cwait();
            *(f4v*)(lh_s + tid * 4) = v;
        }
        if (tid == 0) cstore1(xw + (long)myb * RSTRIDE + XSLOT, allys[myb * NT + t]);
        __syncthreads();
        {
            const int wv = tid >> 6, ln = tid & 63;
            for (int q = 0; q < 3; ++q) {
                const int tt = wv * 3 + q;
                float p = 0.f;
                #pragma unroll
                for (int i2 = 0; i2 < 8; ++i2) {
                    int s = ln + (i2 << 6);
                    p = fmaf(wo_s[s], ftanh_(lh_s[s] + bf2f_(lsb[tt * NS + s])), p);
                }
                #pragma unroll
                for (int off = 32; off >= 1; off >>= 1) p += __shfl_xor(p, off, 64);
                if (ln == 0) e_s[tt] = p + bo0;
            }
        }
        __syncthreads();
        if (tid < 64) {
            float v = (tid < NT) ? e_s[tid] : -1e30f;
            float m = v;
            #pragma unroll
            for (int off = 32; off >= 1; off >>= 1) m = fmaxf(m, __shfl_xor(m, off, 64));
            float ex = (tid < NT) ? __expf(v - m) : 0.0f;
            float ssum = ex;
            #pragma unroll
            for (int off = 32; off >= 1; off >>= 1) ssum += __shfl_xor(ssum, off, 64);
            if (tid < NT) att_s[tid] = ex * frcp_(ssum);
        }
        __syncthreads();
        if (tid >= 512) {   // c[s] on hiddens-holding waves (fp32 in wreg bits)
            float c = 0.f;
            #pragma unroll
            for (int q = 0; q < 12; ++q) {
                f4v hv = H2F_BITS(wreg[q]);
                c = fmaf(att_s[q * 4 + 0], hv.x, c);
                c = fmaf(att_s[q * 4 + 1], hv.y, c);
                c = fmaf(att_s[q * 4 + 2], hv.z, c);
                c = fmaf(att_s[q * 4 + 3], hv.w, c);
            }
            cstore1(xw + (long)myb * RSTRIDE + sS, c);
        }
        gbar(bar, &epoch);

        // ---- C: stage x -> panels; MFMA gi (register weights); GRU gates ----
        float hp = 0.f;
        if (tid < 512) hp = cload1(dw + (long)(g * 32 + rowE) * RSTRIDE + jgE);
        stagePanel(gPanelX, xhi, xlo, tid);
        __syncthreads();
        DO_GEMMC();
        __syncthreads();
        if (tid < 512) {
            float x512f = (float)*(const _Float16*)(xhi + rowE * XROWB + 1024)
                        + (float)*(const _Float16*)(xlo + rowE * XROWB + 1024);
            float gr  = gis[rowE * 17 + jE]       + ghs[rowE * 17 + jE]       + x512f * w512r;
            float gz  = gis[544 + rowE * 17 + jE] + ghs[544 + rowE * 17 + jE] + x512f * w512z;
            float gni = gis[1088 + rowE * 17 + jE] + x512f * w512n;
            float gnh = ghs[1088 + rowE * 17 + jE];
            float rg = fsig_(gr);
            float zg = fsig_(gz);
            float ng = ftanh_(gni + rg * gnh);
            cstore1(dw + (long)(g * 32 + rowE) * RSTRIDE + jgE, (1.f - zg) * ng + zg * hp);
        }
        gbar(bar, &epoch);
    }

    // ================= k_wk_ahead head =================
    for (int kk = 0; kk < KAHEAD; ++kk) {
        {
            float v = 0.f;
            if (tid < NS) v = cload1(dw + (long)myb * RSTRIDE + tid);
            cwait();
            if (tid < NS) lh_s[tid] = v;
        }
        __syncthreads();
        {   // M1: 512 -> 256
            int n = tid & 255, q4 = tid >> 8;
            const float* av = lh_s + q4 * 128;
            const float* wp = W1 + (long)(q4 * 128) * 256 + n;
            float acc = 0.f;
            #pragma unroll 4
            for (int k2 = 0; k2 < 128; ++k2) { acc = fmaf(av[k2], wp[0], acc); wp += 256; }
            h1p[n * 4 + q4] = acc;
        }
        __syncthreads();
        if (tid < 256) {
            float v = h1p[tid * 4] + h1p[tid * 4 + 1] + h1p[tid * 4 + 2] + h1p[tid * 4 + 3];
            h1s[tid] = lrelu_(v + b1[tid]);
        }
        __syncthreads();
        if (tid < 512) {   // M2: 256 -> 128
            int n = tid & 127, q4 = tid >> 7;
            const float* av = h1s + q4 * 64;
            const float* wp = W2 + (long)(q4 * 64) * 128 + n;
            float acc = 0.f;
            #pragma unroll 4
            for (int k2 = 0; k2 < 64; ++k2) { acc = fmaf(av[k2], wp[0], acc); wp += 128; }
            h2p[n * 4 + q4] = acc;
        }
        __syncthreads();
        if (tid < 128) {
            float v = h2p[tid * 4] + h2p[tid * 4 + 1] + h2p[tid * 4 + 2] + h2p[tid * 4 + 3];
            h2s[tid] = lrelu_(v + b2[tid]);
        }
        __syncthreads();
        if (tid < 256) {   // M3: 128 -> 64
            int n = tid & 63, q4 = tid >> 6;
            const float* av = h2s + q4 * 32;
            const float* wp = W3 + (long)(q4 * 32) * 64 + n;
            float acc = 0.f;
            #pragma unroll 4
            for (int k2 = 0; k2 < 32; ++k2) { acc = fmaf(av[k2], wp[0], acc); wp += 64; }
            h3p[n * 4 + q4] = acc;
        }
        __syncthreads();
        if (tid < 64) {    // M3 epilogue + M4
            float v = h3p[tid * 4] + h3p[tid * 4 + 1] + h3p[tid * 4 + 2] + h3p[tid * 4 + 3];
            float h3v = lrelu_(v + b3[tid]);
            float p = h3v * W4[tid];
            #pragma unroll
            for (int off = 32; off >= 1; off >>= 1) p += __shfl_xor(p, off, 64);
            if (tid == 0) {
                float o = lrelu_(p + b4[0]);
                out[myb * KAHEAD + kk] = o;
                cstore1(xw + (long)myb * RSTRIDE + XSLOT, o);
            }
        }
        if (kk < KAHEAD - 1) {
            gbar(bar, &epoch);
            float hp = 0.f;
            if (tid < 512) hp = cload1(dw + (long)(g * 32 + rowE) * RSTRIDE + jgE);
            stagePanel(gPanelD, xhi, xlo, tid);
            __syncthreads();
            DO_GEMMA(false);
            __syncthreads();
            stagePanel(gPanelX, xhi, xlo, tid);
            __syncthreads();
            DO_GEMMC();
            __syncthreads();
            if (tid < 512) {
                float x512f = (float)*(const _Float16*)(xhi + rowE * XROWB + 1024)
                            + (float)*(const _Float16*)(xlo + rowE * XROWB + 1024);
                float gr  = gis[rowE * 17 + jE]       + ghs[rowE * 17 + jE]       + x512f * w512r;
                float gz  = gis[544 + rowE * 17 + jE] + ghs[544 + rowE * 17 + jE] + x512f * w512z;
                float gni = gis[1088 + rowE * 17 + jE] + x512f * w512n;
                float gnh = ghs[1088 + rowE * 17 + jE];
                float rg = fsig_(gr);
                float zg = fsig_(gz);
                float ng = ftanh_(gni + rg * gnh);
                cstore1(dw + (long)(g * 32 + rowE) * RSTRIDE + jgE, (1.f - zg) * ng + zg * hp);
            }
            gbar(bar, &epoch);
        }
    }
}

// ---------------- host ----------------
extern "C" void kernel_launch(void* const* d_in, const int* in_sizes, int n_in,
                              void* d_out, int out_size, void* d_ws, size_t ws_size,
                              hipStream_t stream) {
    const float* hiddens = (const float*)d_in[0];
    const float* allys   = (const float*)d_in[1];
    const float* Wh   = (const float*)d_in[3];
    const float* bh   = (const float*)d_in[4];
    const float* Ws   = (const float*)d_in[5];
    const float* bs   = (const float*)d_in[6];
    const float* Wo   = (const float*)d_in[7];
    const float* bo   = (const float*)d_in[8];
    const float* W_ih = (const float*)d_in[9];
    const float* W_hh = (const float*)d_in[10];
    const float* b_ih = (const float*)d_in[11];
    const float* b_hh = (const float*)d_in[12];
    const float* W1 = (const float*)d_in[13];
    const float* b1 = (const float*)d_in[14];
    const float* W2 = (const float*)d_in[15];
    const float* b2 = (const float*)d_in[16];
    const float* W3 = (const float*)d_in[17];
    const float* b3 = (const float*)d_in[18];
    const float* W4 = (const float*)d_in[19];
    const float* b4 = (const float*)d_in[20];
    float* wsf = (float*)d_ws;
    float* outf = (float*)d_out;

    if (ws_size < (size_t)WS_FLOATS * sizeof(float)) {
        fprintf(stderr, "kernel_launch: workspace too small (%zu < %zu)\n",
                ws_size, (size_t)WS_FLOATS * sizeof(float));
        return;
    }

    prep_kernel<<<dim3(2048), dim3(256), 0, stream>>>(W_hh, W_ih, Wh, Ws, wsf);

    (void)hipFuncSetAttribute((const void*)fused_kernel,
                              hipFuncAttributeMaxDynamicSharedMemorySize, LDS_BYTES);

    void* args[] = { &hiddens, &allys, &bs, &Wo, &bo, &bh,
                     &b_ih, &b_hh, &W_ih, &W1, &b1, &W2, &b2, &W3, &b3, &W4, &b4,
                     &wsf, &outf };
    hipError_t e = hipLaunchCooperativeKernel((void*)fused_kernel,
                                              dim3(NBLOCKS), dim3(NTHREADS),
                                              args, LDS_BYTES, stream);
    if (e != hipSuccess) {
        fprintf(stderr, "coop launch failed (%d); plain fallback\n", (int)e);
        (void)hipGetLastError();
        fused_kernel<<<dim3(NBLOCKS), dim3(NTHREADS), LDS_BYTES, stream>>>(
            hiddens, allys, bs, Wo, bo, bh, b_ih, b_hh, W_ih,
            W1, b1, W2, b2, W3, b3, W4, b4, wsf, outf);
    }
}